// Round 9
// baseline (3658.924 us; speedup 1.0000x reference)
//
#include <hip/hip_runtime.h>
#include <hip/hip_bf16.h>
#include <cstdint>

// ReportDecoder: B=512,S=49,E=1024,H=1024,V2=16,L=64,T=48, D_IN=1105
// Round 9: r8 with ONE change — XCD-contiguous cb mapping so no 64B h-line is
// written by more than one XCD (kills the 2x HBM write amplification seen in r8):
//   slot = blk>>3; rb = slot>>4 (0..3); cb = xcd*16 + (slot&15) (0..127).
// Geometry unchanged: 512 blocks, 2 blocks/CU, 64KB resident W slice, 16x16x32 MFMA.

typedef __bf16 bf16_t;
typedef bf16_t bf16x8 __attribute__((ext_vector_type(8)));
typedef bf16_t bf16x4 __attribute__((ext_vector_type(4)));
typedef float  f32x4  __attribute__((ext_vector_type(4)));

#define Bn   512
#define Sn   49
#define En   1024
#define Hn   1024
#define Ln   64
#define Tn   48
#define DINn 1105
#define NOn  1090

#define BM   64
#define LDSP 72     // padded K-stride for 64-wide tiles in init/out GEMMs

__device__ __forceinline__ float sigm(float x){ return 1.0f / (1.0f + __expf(-x)); }

// ---------- image mean ----------
__global__ __launch_bounds__(256) void k_mean(const float* __restrict__ image,
                                              bf16_t* __restrict__ imb){
  int b  = blockIdx.x;
  int e0 = threadIdx.x * 4;
  const float* p = image + (size_t)b * (Sn * En) + e0;
  float4 acc = make_float4(0.f, 0.f, 0.f, 0.f);
  for (int s = 0; s < Sn; ++s){
    float4 v = *reinterpret_cast<const float4*>(p + (size_t)s * En);
    acc.x += v.x; acc.y += v.y; acc.z += v.z; acc.w += v.w;
  }
  const float inv = 1.0f / 49.0f;
  bf16x4 o;
  o[0] = (bf16_t)(acc.x * inv); o[1] = (bf16_t)(acc.y * inv);
  o[2] = (bf16_t)(acc.z * inv); o[3] = (bf16_t)(acc.w * inv);
  *reinterpret_cast<bf16x4*>(imb + (size_t)b * En + e0) = o;
}

// ---------- fp32 -> bf16 conversions ----------
__global__ __launch_bounds__(256) void k_convert(
    const float* __restrict__ w_hh,  const float* __restrict__ fc_h_w,
    const float* __restrict__ fc_m_w,const float* __restrict__ fc_w,
    const float* __restrict__ label, const float* __restrict__ w_ih,
    bf16_t* __restrict__ whhb,  bf16_t* __restrict__ fchwb,
    bf16_t* __restrict__ fcmwb, bf16_t* __restrict__ fcwb,
    bf16_t* __restrict__ labelb,bf16_t* __restrict__ wimgb,
    bf16_t* __restrict__ wlabb){
  const int NV0 = 4096 * 1024 / 4;
  const int NV1 = NV0 + 1024 * 1024 / 4;
  const int NV2 = NV1 + 1024 * 1024 / 4;
  const int NV3 = NV2 + 1090 * 1024 / 4;
  const int NV4 = NV3 + 512 * 49 * 64 / 4;
  const int NS5 = NV4 + 4096 * 1024;
  const int NS6 = NS5 + 4096 * 64;
  int stride = gridDim.x * blockDim.x;
  for (int i = blockIdx.x * blockDim.x + threadIdx.x; i < NS6; i += stride){
    if (i < NV4){
      const float* src; bf16_t* dst; int j;
      if      (i < NV0){ src = w_hh;   dst = whhb;  j = i; }
      else if (i < NV1){ src = fc_h_w; dst = fchwb; j = i - NV0; }
      else if (i < NV2){ src = fc_m_w; dst = fcmwb; j = i - NV1; }
      else if (i < NV3){ src = fc_w;   dst = fcwb;  j = i - NV2; }
      else             { src = label;  dst = labelb;j = i - NV3; }
      float4 v = *reinterpret_cast<const float4*>(src + (size_t)j * 4);
      bf16x4 o;
      o[0] = (bf16_t)v.x; o[1] = (bf16_t)v.y; o[2] = (bf16_t)v.z; o[3] = (bf16_t)v.w;
      *reinterpret_cast<bf16x4*>(dst + (size_t)j * 4) = o;
    } else if (i < NS5){
      int j = i - NV4; int n = j >> 10, k = j & 1023;
      wimgb[j] = (bf16_t)w_ih[(size_t)n * DINn + k];
    } else {
      int j = i - NS5; int n = j >> 6, k = j & 63;
      wlabb[j] = (bf16_t)w_ih[(size_t)n * DINn + 1041 + k];
    }
  }
}

// ---------- xconst pre-pass + barrier-state zero ----------
__global__ __launch_bounds__(256) void k_vpc(const float* __restrict__ w_ih,
                                             const float* __restrict__ vp,
                                             const float* __restrict__ b_ih,
                                             const float* __restrict__ b_hh,
                                             float* __restrict__ xconst,
                                             unsigned* __restrict__ bar){
  if (blockIdx.x < 4) bar[blockIdx.x * 256 + threadIdx.x] = 0u;  // 1024 u32
  int idx = blockIdx.x * 256 + threadIdx.x;
  int b = idx >> 12, n = idx & 4095;
  float acc = b_ih[n] + b_hh[n];
  const float* w = w_ih + (size_t)n * DINn + En;
  const float* v = vp + b * 16;
  #pragma unroll
  for (int j = 0; j < 16; ++j) acc += v[j] * w[j];
  xconst[idx] = acc;
}

// ---------- shared GEMM helpers (64x128 tile, 4 waves, 16x16x32) ----------
__device__ __forceinline__ void stageA(bf16_t* sA, const bf16_t* gptr, int ld, int tid){
  #pragma unroll
  for (int i = 0; i < 2; ++i){
    int idx = tid + i * 256;
    int r = idx >> 3, v = idx & 7;
    *reinterpret_cast<bf16x8*>(sA + r * LDSP + v * 8) =
      *reinterpret_cast<const bf16x8*>(gptr + (size_t)r * ld + v * 8);
  }
}

__device__ __forceinline__ void mma_tile(const bf16_t* sA, const bf16_t* sB,
                                         f32x4 (&acc)[4][2], int lane, int w){
  int lr = lane & 15;
  int lk = (lane >> 4) * 8;
  #pragma unroll
  for (int kk = 0; kk < 2; ++kk){
    bf16x8 a[4], bb[2];
    #pragma unroll
    for (int mi = 0; mi < 4; ++mi)
      a[mi] = *reinterpret_cast<const bf16x8*>(sA + (mi * 16 + lr) * LDSP + kk * 32 + lk);
    #pragma unroll
    for (int ni = 0; ni < 2; ++ni)
      bb[ni] = *reinterpret_cast<const bf16x8*>(sB + (w * 32 + ni * 16 + lr) * LDSP + kk * 32 + lk);
    #pragma unroll
    for (int mi = 0; mi < 4; ++mi)
      #pragma unroll
      for (int ni = 0; ni < 2; ++ni)
        acc[mi][ni] = __builtin_amdgcn_mfma_f32_16x16x32_bf16(a[mi], bb[ni], acc[mi][ni], 0, 0, 0);
  }
}

// ---------- init GEMM: h0, m0, xconst += im@Wimg^T ----------
__global__ __launch_bounds__(256) void k_init_gemm(
    const bf16_t* __restrict__ imb,  const bf16_t* __restrict__ fchw,
    const bf16_t* __restrict__ fcmw, const bf16_t* __restrict__ wimg,
    const float* __restrict__ fc_h_b,const float* __restrict__ fc_m_b,
    bf16_t* __restrict__ h0, float* __restrict__ m0, float* __restrict__ xconst){
  __shared__ __align__(16) unsigned char smem[(BM + 128) * LDSP * 2];
  bf16_t* sA = (bf16_t*)smem;
  bf16_t* sB = (bf16_t*)(smem + BM * LDSP * 2);
  int tid = threadIdx.x;
  int cb = blockIdx.x, rb = blockIdx.y;
  int nBase = cb * 128;
  const bf16_t* Bsrc; int nOff;
  if      (nBase < 1024){ Bsrc = fchw; nOff = nBase; }
  else if (nBase < 2048){ Bsrc = fcmw; nOff = nBase - 1024; }
  else                  { Bsrc = wimg; nOff = nBase - 2048; }

  f32x4 acc[4][2] = {};
  int lane = tid & 63, w = tid >> 6;
  for (int kt = 0; kt < 16; ++kt){
    stageA(sA, imb + (size_t)(rb * 64) * 1024 + kt * 64, 1024, tid);
    #pragma unroll
    for (int i = 0; i < 4; ++i){
      int idx = tid + i * 256;
      int r = idx >> 3, v = idx & 7;
      *reinterpret_cast<bf16x8*>(sB + r * LDSP + v * 8) =
        *reinterpret_cast<const bf16x8*>(Bsrc + (size_t)(nOff + r) * 1024 + kt * 64 + v * 8);
    }
    __syncthreads();
    mma_tile(sA, sB, acc, lane, w);
    __syncthreads();
  }
  int lr = lane & 15, lg = lane >> 4;
  #pragma unroll
  for (int mi = 0; mi < 4; ++mi)
    #pragma unroll
    for (int ni = 0; ni < 2; ++ni)
      #pragma unroll
      for (int r = 0; r < 4; ++r){
        int ng   = nBase + w * 32 + ni * 16 + lr;
        int rowg = rb * 64 + mi * 16 + lg * 4 + r;
        float v = acc[mi][ni][r];
        if (ng < 1024){
          h0[(size_t)rowg * 1024 + ng] = (bf16_t)tanhf(v + fc_h_b[ng]);
        } else if (ng < 2048){
          int n = ng - 1024;
          m0[(size_t)rowg * 1024 + n] = tanhf(v + fc_m_b[n]);
        } else {
          int n = ng - 2048;
          xconst[(size_t)rowg * 4096 + n] += v;
        }
      }
}

// ---------- two-level grid barrier (r7 protocol, 512 blocks) ----------
// bar[0]=gen, bar[32]=gcnt, bar[64+16x]=xcnt[x] (x = blk&7: 64-block XCD chains).
__device__ __forceinline__ void grid_barrier(unsigned* __restrict__ bar, unsigned step){
  __threadfence();            // release: every thread drains its h stores
  __syncthreads();
  if (threadIdx.x == 0){
    unsigned x = (unsigned)blockIdx.x & 7u;
    unsigned* xcnt = bar + 64 + 16 * x;
    unsigned* gcnt = bar + 32;
    unsigned* gen  = bar;
    if (__hip_atomic_fetch_add(xcnt, 1u, __ATOMIC_RELAXED, __HIP_MEMORY_SCOPE_AGENT) == 63u){
      __hip_atomic_store(xcnt, 0u, __ATOMIC_RELAXED, __HIP_MEMORY_SCOPE_AGENT);
      if (__hip_atomic_fetch_add(gcnt, 1u, __ATOMIC_RELAXED, __HIP_MEMORY_SCOPE_AGENT) == 7u){
        __hip_atomic_store(gcnt, 0u, __ATOMIC_RELAXED, __HIP_MEMORY_SCOPE_AGENT);
        __hip_atomic_store(gen, step + 1u, __ATOMIC_RELEASE, __HIP_MEMORY_SCOPE_AGENT);
      }
    }
    while (__hip_atomic_load(gen, __ATOMIC_RELAXED, __HIP_MEMORY_SCOPE_AGENT) <= step)
      __builtin_amdgcn_s_sleep(2);
    __threadfence();          // acquire side (r3/r7-proven placement)
  }
  __syncthreads();
}

// ---------- persistent kernel: all 48 LSTM steps ----------
// 512 blocks x 256 thr, 2 blocks/CU. slot=blk>>3; rb=slot>>4 (128 rows);
// cb = xcd*16 + (slot&15) in [0,128): 8 hcols x 4 gates = 32 n-rows (64 KB LDS).
// XCD-contiguous cb: every 64B h-line is written by a single XCD (no line split).
// Wave w: rows w*32..+31 via 16x16x32 MFMA; shfl_xor(8) completes the gate set.
__global__ __launch_bounds__(256, 2) void k_steps(
    bf16_t* hs,                         // (49, 512, 1024); hs[0]=h0
    const bf16_t* __restrict__ whh,     // (4096, 1024)
    const bf16_t* __restrict__ wlab,    // (4096, 64)
    const bf16_t* __restrict__ labelb,  // (512, 49, 64)
    const float*  __restrict__ xconst,  // (512, 4096)
    const float*  __restrict__ w_ih,    // (4096, 1105), begin col 1040
    const float*  __restrict__ m_init,  // (512, 1024)
    unsigned* __restrict__ bar){
  __shared__ __align__(16) bf16_t sB[32 * 1024];   // 64 KB, swizzled
  __shared__ __align__(16) bf16_t sLab[32 * 64];   // 4 KB, swizzled
  int tid  = threadIdx.x;
  int blk  = blockIdx.x;
  int xcd  = blk & 7;
  int slot = blk >> 3;
  int rb   = slot >> 4;                 // 0..3
  int cb   = xcd * 16 + (slot & 15);    // 0..127, XCD-contiguous
  int lane = tid & 63, w = tid >> 6;
  int lr   = lane & 15;        // frag row (A: batch row; B: n-row within 16)
  int h4   = lane >> 4;        // 0..3: k-chunk selector
  int gb   = (lane >> 3) & 1;  // gate parity within col-frag

  // stage resident W slices (swizzled: 16B unit v -> v ^ sw(r), sw=(r^(r>>3))&7)
  // n_local r = g*8 + j  ->  whh row g*1024 + cb*8 + j
  for (int i = tid; i < 4096; i += 256){
    int r = i >> 7, v = i & 127;
    int sw = (r ^ (r >> 3)) & 7;
    *reinterpret_cast<bf16x8*>(sB + r * 1024 + (v ^ sw) * 8) =
      *reinterpret_cast<const bf16x8*>(whh + (size_t)((r >> 3) * 1024 + cb * 8 + (r & 7)) * 1024 + v * 8);
  }
  {
    int i = tid;
    if (i < 256){
      int r = i >> 3, v = i & 7;
      int sw = (r ^ (r >> 3)) & 7;
      *reinterpret_cast<bf16x8*>(sLab + r * 64 + (v ^ sw) * 8) =
        *reinterpret_cast<const bf16x8*>(wlab + (size_t)((r >> 3) * 1024 + cb * 8 + (r & 7)) * 64 + v * 8);
    }
  }

  // per-lane constants
  int hcolG = cb * 8 + (lane & 7);
  int row0w = rb * 128 + w * 32;
  float xc[4][8], mreg[8], wb[4];
  #pragma unroll
  for (int g = 0; g < 4; ++g)
    wb[g] = w_ih[(size_t)(g * 1024 + hcolG) * DINn + 1040];
  #pragma unroll
  for (int mi = 0; mi < 2; ++mi)
    #pragma unroll
    for (int r = 0; r < 4; ++r){
      int qi = mi * 4 + r;
      int rowG = row0w + mi * 16 + h4 * 4 + r;
      mreg[qi] = m_init[(size_t)rowG * 1024 + hcolG];
      #pragma unroll
      for (int g = 0; g < 4; ++g)
        xc[g][qi] = xconst[(size_t)rowG * 4096 + g * 1024 + hcolG];
    }
  __syncthreads();

  // LDS read bases + swizzle keys per col-frag
  int swn0 = (lr ^ (lr >> 3)) & 7;
  int rn1  = 16 + lr;
  int swn1 = (rn1 ^ (rn1 >> 3)) & 7;
  const bf16_t* sb0 = sB + (size_t)lr  * 1024;
  const bf16_t* sb1 = sB + (size_t)rn1 * 1024;
  const bf16_t* sl0 = sLab + (size_t)lr  * 64;
  const bf16_t* sl1 = sLab + (size_t)rn1 * 64;
  const bf16_t* aBase = hs + (size_t)(row0w + lr) * Hn + h4 * 8;
  const bf16_t* lBase = labelb + (size_t)(row0w + lr) * (Sn * Ln) + h4 * 8;

  for (int t = 0; t < Tn; ++t){
    const bf16_t* aptr = aBase + (size_t)t * (Bn * Hn);
    f32x4 acc[2][2] = {};
    #pragma unroll 4
    for (int kt = 0; kt < 16; ++kt){
      bf16x8 a[2][2], b0[2], b1[2];
      #pragma unroll
      for (int mi = 0; mi < 2; ++mi)
        #pragma unroll
        for (int kk = 0; kk < 2; ++kk)
          a[mi][kk] = *reinterpret_cast<const bf16x8*>(aptr + (size_t)mi * 16 * Hn + kt * 64 + kk * 32);
      #pragma unroll
      for (int kk = 0; kk < 2; ++kk){
        int u = kt * 8 + kk * 4 + h4;
        b0[kk] = *reinterpret_cast<const bf16x8*>(sb0 + (u ^ swn0) * 8);
        b1[kk] = *reinterpret_cast<const bf16x8*>(sb1 + (u ^ swn1) * 8);
      }
      #pragma unroll
      for (int kk = 0; kk < 2; ++kk)
        #pragma unroll
        for (int mi = 0; mi < 2; ++mi){
          acc[mi][0] = __builtin_amdgcn_mfma_f32_16x16x32_bf16(a[mi][kk], b0[kk], acc[mi][0], 0, 0, 0);
          acc[mi][1] = __builtin_amdgcn_mfma_f32_16x16x32_bf16(a[mi][kk], b1[kk], acc[mi][1], 0, 0, 0);
        }
    }
    if (t > 0){
      const bf16_t* lp = lBase + (size_t)(t - 1) * 64;
      bf16x8 a[2][2], b0[2], b1[2];
      #pragma unroll
      for (int mi = 0; mi < 2; ++mi)
        #pragma unroll
        for (int kk = 0; kk < 2; ++kk)
          a[mi][kk] = *reinterpret_cast<const bf16x8*>(lp + (size_t)mi * 16 * (Sn * Ln) + kk * 32);
      #pragma unroll
      for (int kk = 0; kk < 2; ++kk){
        int u = kk * 4 + h4;
        b0[kk] = *reinterpret_cast<const bf16x8*>(sl0 + (u ^ swn0) * 8);
        b1[kk] = *reinterpret_cast<const bf16x8*>(sl1 + (u ^ swn1) * 8);
      }
      #pragma unroll
      for (int kk = 0; kk < 2; ++kk)
        #pragma unroll
        for (int mi = 0; mi < 2; ++mi){
          acc[mi][0] = __builtin_amdgcn_mfma_f32_16x16x32_bf16(a[mi][kk], b0[kk], acc[mi][0], 0, 0, 0);
          acc[mi][1] = __builtin_amdgcn_mfma_f32_16x16x32_bf16(a[mi][kk], b1[kk], acc[mi][1], 0, 0, 0);
        }
    }

    // gate exchange: partner lane^8 holds gates {gb^1, gb^1+2} for same (rows, hcol)
    float oth[2][2][4];
    #pragma unroll
    for (int mi = 0; mi < 2; ++mi)
      #pragma unroll
      for (int ni = 0; ni < 2; ++ni)
        #pragma unroll
        for (int r = 0; r < 4; ++r)
          oth[mi][ni][r] = __shfl_xor(acc[mi][ni][r], 8, 64);

    bf16_t* hO = hs + (size_t)(t + 1) * (Bn * Hn);
    #pragma unroll
    for (int mi = 0; mi < 2; ++mi)
      #pragma unroll
      for (int r = 0; r < 4; ++r){
        int qi = mi * 4 + r;
        float vi, vf, vg, vo;
        if (gb == 0){ vi = acc[mi][0][r]; vf = oth[mi][0][r]; vg = acc[mi][1][r]; vo = oth[mi][1][r]; }
        else        { vi = oth[mi][0][r]; vf = acc[mi][0][r]; vg = oth[mi][1][r]; vo = acc[mi][1][r]; }
        float gi = vi + xc[0][qi];
        float gf = vf + xc[1][qi];
        float gg = vg + xc[2][qi];
        float go = vo + xc[3][qi];
        if (t == 0){ gi += wb[0]; gf += wb[1]; gg += wb[2]; go += wb[3]; }
        float mn = sigm(gf) * mreg[qi] + sigm(gi) * tanhf(gg);
        mreg[qi] = mn;
        float hn = sigm(go) * tanhf(mn);
        hO[(size_t)(row0w + mi * 16 + h4 * 4 + r) * 1024 + hcolG] = (bf16_t)hn;
      }
    if (t < Tn - 1)
      grid_barrier(bar, (unsigned)t);
  }
}

// ---------- batched out GEMM + activations + mask + scatter ----------
__global__ __launch_bounds__(256) void k_out(
    const bf16_t* __restrict__ h,      // hs + 512*1024: 24576 x 1024
    const bf16_t* __restrict__ fcwb,
    const float* __restrict__ fc_b, const int* __restrict__ length,
    float* __restrict__ out){
  __shared__ __align__(16) unsigned char smem[(BM + 128) * LDSP * 2];
  bf16_t* sA = (bf16_t*)smem;
  bf16_t* sB = (bf16_t*)(smem + BM * LDSP * 2);
  int tid = threadIdx.x;
  int cb = blockIdx.x, rb = blockIdx.y;
  f32x4 acc[4][2] = {};
  int lane = tid & 63, w = tid >> 6;
  for (int kt = 0; kt < 16; ++kt){
    stageA(sA, h + (size_t)(rb * 64) * 1024 + kt * 64, 1024, tid);
    #pragma unroll
    for (int i = 0; i < 4; ++i){
      int idx = tid + i * 256;
      int r = idx >> 3, v = idx & 7;
      int n = cb * 128 + r;
      bf16x8 val = {};
      if (n < NOn)
        val = *reinterpret_cast<const bf16x8*>(fcwb + (size_t)n * 1024 + kt * 64 + v * 8);
      *reinterpret_cast<bf16x8*>(sB + r * LDSP + v * 8) = val;
    }
    __syncthreads();
    mma_tile(sA, sB, acc, lane, w);
    __syncthreads();
  }
  int lr = lane & 15, lg = lane >> 4;
  #pragma unroll
  for (int mi = 0; mi < 4; ++mi)
    #pragma unroll
    for (int ni = 0; ni < 2; ++ni)
      #pragma unroll
      for (int r = 0; r < 4; ++r){
        int ng = cb * 128 + w * 32 + ni * 16 + lr;
        if (ng >= NOn) continue;
        int rg = rb * 64 + mi * 16 + lg * 4 + r;
        int tt = rg >> 9, b = rg & 511;
        float v = acc[mi][ni][r] + fc_b[ng];
        float mask = (tt < length[b]) ? 1.0f : 0.0f;
        if      (ng < 64)    out[(size_t)rg * 64 + ng] = sigm(v) * mask;
        else if (ng < 1088)  out[(size_t)1572864 + (size_t)rg * 1024 + (ng - 64)] = fmaxf(v, 0.f) * mask;
        else if (ng == 1088) out[(size_t)26738688 + rg] = sigm(v) * mask;
        else                 out[(size_t)26763264 + rg] = __expf(v) * mask;
      }
}

extern "C" void kernel_launch(void* const* d_in, const int* in_sizes, int n_in,
                              void* d_out, int out_size, void* d_ws, size_t ws_size,
                              hipStream_t stream){
  const float* image  = (const float*)d_in[0];
  const float* vp     = (const float*)d_in[1];
  const float* label  = (const float*)d_in[2];
  const int*   length = (const int*)  d_in[3];
  const float* fc_h_w = (const float*)d_in[4];
  const float* fc_h_b = (const float*)d_in[5];
  const float* fc_m_w = (const float*)d_in[6];
  const float* fc_m_b = (const float*)d_in[7];
  const float* w_ih   = (const float*)d_in[8];
  const float* w_hh   = (const float*)d_in[9];
  const float* b_ih   = (const float*)d_in[10];
  const float* b_hh   = (const float*)d_in[11];
  const float* fc_w   = (const float*)d_in[12];
  const float* fc_b   = (const float*)d_in[13];
  float* out = (float*)d_out;

  char* ws = (char*)d_ws;
  bf16_t* imb    = (bf16_t*)(ws + 0);           // 1 MB
  bf16_t* hs     = (bf16_t*)(ws + 1048576);     // 51.4 MB
  float*  m      = (float*) (ws + 52428800);    // 2 MB
  float*  xconst = (float*) (ws + 54525952);    // 8 MB
  bf16_t* whhb   = (bf16_t*)(ws + 62914560);    // 8 MB
  bf16_t* wimgb  = (bf16_t*)(ws + 71303168);    // 8 MB
  bf16_t* wlabb  = (bf16_t*)(ws + 79691776);    // 0.5 MB
  bf16_t* fchwb  = (bf16_t*)(ws + 80216064);    // 2 MB
  bf16_t* fcmwb  = (bf16_t*)(ws + 82313216);    // 2 MB
  bf16_t* fcwb   = (bf16_t*)(ws + 84410368);    // 2.2 MB
  bf16_t* labelb = (bf16_t*)(ws + 86642688);    // 3.2 MB (ends 89853952)
  unsigned* bar  = (unsigned*)(ws + 89853952);  // 4 KB barrier state

  k_mean   <<<dim3(512),  dim3(256), 0, stream>>>(image, imb);
  k_convert<<<dim3(2048), dim3(256), 0, stream>>>(w_hh, fc_h_w, fc_m_w, fc_w, label, w_ih,
                                                  whhb, fchwb, fcmwb, fcwb, labelb, wimgb, wlabb);
  k_vpc    <<<dim3(8192), dim3(256), 0, stream>>>(w_ih, vp, b_ih, b_hh, xconst, bar);
  k_init_gemm<<<dim3(48, 8), dim3(256), 0, stream>>>(imb, fchwb, fcmwb, wimgb,
                                                     fc_h_b, fc_m_b, hs, m, xconst);

  bf16_t* hs_p = hs;
  const bf16_t* whh_p = whhb;
  const bf16_t* wlab_p = wlabb;
  const bf16_t* labelb_p = labelb;
  const float* xconst_p = xconst;
  const float* wih_p = w_ih;
  const float* m_p = m;
  unsigned* bar_p = bar;
  void* kargs[8] = { (void*)&hs_p, (void*)&whh_p, (void*)&wlab_p, (void*)&labelb_p,
                     (void*)&xconst_p, (void*)&wih_p, (void*)&m_p, (void*)&bar_p };
  (void)hipLaunchCooperativeKernel(reinterpret_cast<void*>(k_steps),
                                   dim3(512), dim3(256), kargs, 0, stream);

  k_out<<<dim3(9, 384), dim3(256), 0, stream>>>(hs + (size_t)512 * 1024, fcwb, fc_b, length, out);
}

// Round 10
// 1385.842 us; speedup vs baseline: 2.6402x; 2.6402x over previous
//
#include <hip/hip_runtime.h>
#include <hip/hip_bf16.h>
#include <cstdint>

// ReportDecoder: B=512,S=49,E=1024,H=1024,V2=16,L=64,T=48, D_IN=1105
// Round 10: abandon persistent grid-barrier kernel (cross-XCD coherence cost is
// structural: ~30us/step of L2 wb/inv + coherence-point RMWs). Per-step kernel
// launches instead: CP does one flush/inv per dispatch; graph replay gaps ~2-3us.
//   - concat-K: hs rows = [h(1024) | lab_t(64)] stride 1088; whhx = [W_hh | W_lab],
//     so gates = one GEMM with K=1088 = 17x64.
//   - k_step: 64x128 tile, global_load_lds width-16 staging, 2-phase loop,
//     fused xconst+begin+LSTM cell epilogue (r1-proven numerics).
//   - k_out batched over all 48 steps (unchanged, stride 1088).

typedef __bf16 bf16_t;
typedef bf16_t bf16x8 __attribute__((ext_vector_type(8)));
typedef bf16_t bf16x4 __attribute__((ext_vector_type(4)));
typedef float  f32x4  __attribute__((ext_vector_type(4)));

#define Bn    512
#define Sn    49
#define En    1024
#define Hn    1024
#define Ln    64
#define Tn    48
#define DINn  1105
#define NOn   1090
#define HLD   1088          // h row stride (1024 h + 64 label)
#define HSTEP 557056        // 512*1088 elements per step slab

#define BM   64
#define LDSP 72             // padded K-stride for init/out GEMM LDS tiles

__device__ __forceinline__ float sigm(float x){ return 1.0f / (1.0f + __expf(-x)); }

// ---------- image mean ----------
__global__ __launch_bounds__(256) void k_mean(const float* __restrict__ image,
                                              bf16_t* __restrict__ imb){
  int b  = blockIdx.x;
  int e0 = threadIdx.x * 4;
  const float* p = image + (size_t)b * (Sn * En) + e0;
  float4 acc = make_float4(0.f, 0.f, 0.f, 0.f);
  for (int s = 0; s < Sn; ++s){
    float4 v = *reinterpret_cast<const float4*>(p + (size_t)s * En);
    acc.x += v.x; acc.y += v.y; acc.z += v.z; acc.w += v.w;
  }
  const float inv = 1.0f / 49.0f;
  bf16x4 o;
  o[0] = (bf16_t)(acc.x * inv); o[1] = (bf16_t)(acc.y * inv);
  o[2] = (bf16_t)(acc.z * inv); o[3] = (bf16_t)(acc.w * inv);
  *reinterpret_cast<bf16x4*>(imb + (size_t)b * En + e0) = o;
}

// ---------- conversions: whhx concat, fc weights, wimg, label scatter into hs ----------
__global__ __launch_bounds__(256) void k_convert(
    const float* __restrict__ w_hh,  const float* __restrict__ fc_h_w,
    const float* __restrict__ fc_m_w,const float* __restrict__ fc_w,
    const float* __restrict__ label, const float* __restrict__ w_ih,
    bf16_t* __restrict__ whhx,  bf16_t* __restrict__ fchwb,
    bf16_t* __restrict__ fcmwb, bf16_t* __restrict__ fcwb,
    bf16_t* __restrict__ wimgb, bf16_t* __restrict__ hs){
  const int E0 = 4096 * 1088;            // whhx = [W_hh | W_lab]
  const int E1 = E0 + 1024 * 1024;       // fchwb
  const int E2 = E1 + 1024 * 1024;       // fcmwb
  const int E3 = E2 + 1090 * 1024;       // fcwb
  const int E4 = E3 + 4096 * 1024;       // wimgb (W_ih image part)
  const int E5 = E4 + 48 * 512 * 64;     // labels into hs[t][*][1024..1088]
  int stride = gridDim.x * blockDim.x;
  for (int i = blockIdx.x * blockDim.x + threadIdx.x; i < E5; i += stride){
    if (i < E0){
      int n = i / 1088, k = i - n * 1088;
      float v = (k < 1024) ? w_hh[(size_t)n * 1024 + k]
                           : w_ih[(size_t)n * DINn + 1041 + (k - 1024)];
      whhx[i] = (bf16_t)v;
    } else if (i < E1){ int j = i - E0; fchwb[j] = (bf16_t)fc_h_w[j]; }
    else if (i < E2){ int j = i - E1; fcmwb[j] = (bf16_t)fc_m_w[j]; }
    else if (i < E3){ int j = i - E2; fcwb[j]  = (bf16_t)fc_w[j]; }
    else if (i < E4){
      int j = i - E3; int n = j >> 10, k = j & 1023;
      wimgb[j] = (bf16_t)w_ih[(size_t)n * DINn + k];
    } else {
      int j = i - E4;
      int t = j >> 15, rem = j & 32767, row = rem >> 6, c = rem & 63;
      float v = (t == 0) ? 0.f : label[(size_t)row * (Sn * Ln) + (t - 1) * 64 + c];
      hs[((size_t)t * 512 + row) * HLD + 1024 + c] = (bf16_t)v;
    }
  }
}

// ---------- xconst pre-pass: bias + view_position dot ----------
__global__ __launch_bounds__(256) void k_vpc(const float* __restrict__ w_ih,
                                             const float* __restrict__ vp,
                                             const float* __restrict__ b_ih,
                                             const float* __restrict__ b_hh,
                                             float* __restrict__ xconst){
  int idx = blockIdx.x * 256 + threadIdx.x;
  int b = idx >> 12, n = idx & 4095;
  float acc = b_ih[n] + b_hh[n];
  const float* w = w_ih + (size_t)n * DINn + En;
  const float* v = vp + b * 16;
  #pragma unroll
  for (int j = 0; j < 16; ++j) acc += v[j] * w[j];
  xconst[idx] = acc;
}

// ---------- shared GEMM helpers (padded-LDS variant for init/out) ----------
__device__ __forceinline__ void stageA(bf16_t* sA, const bf16_t* gptr, int ld, int tid){
  #pragma unroll
  for (int i = 0; i < 2; ++i){
    int idx = tid + i * 256;
    int r = idx >> 3, v = idx & 7;
    *reinterpret_cast<bf16x8*>(sA + r * LDSP + v * 8) =
      *reinterpret_cast<const bf16x8*>(gptr + (size_t)r * ld + v * 8);
  }
}

__device__ __forceinline__ void mma_tile(const bf16_t* sA, const bf16_t* sB,
                                         f32x4 (&acc)[4][2], int lane, int w){
  int lr = lane & 15;
  int lk = (lane >> 4) * 8;
  #pragma unroll
  for (int kk = 0; kk < 2; ++kk){
    bf16x8 a[4], bb[2];
    #pragma unroll
    for (int mi = 0; mi < 4; ++mi)
      a[mi] = *reinterpret_cast<const bf16x8*>(sA + (mi * 16 + lr) * LDSP + kk * 32 + lk);
    #pragma unroll
    for (int ni = 0; ni < 2; ++ni)
      bb[ni] = *reinterpret_cast<const bf16x8*>(sB + (w * 32 + ni * 16 + lr) * LDSP + kk * 32 + lk);
    #pragma unroll
    for (int mi = 0; mi < 4; ++mi)
      #pragma unroll
      for (int ni = 0; ni < 2; ++ni)
        acc[mi][ni] = __builtin_amdgcn_mfma_f32_16x16x32_bf16(a[mi], bb[ni], acc[mi][ni], 0, 0, 0);
  }
}

// linear-LDS variant for k_step (global_load_lds needs linear layout)
__device__ __forceinline__ void mma_tile_lin(const bf16_t* sA, const bf16_t* sB,
                                             f32x4 (&acc)[4][2], int lane, int w){
  int lr = lane & 15;
  int lk = (lane >> 4) * 8;
  #pragma unroll
  for (int kk = 0; kk < 2; ++kk){
    bf16x8 a[4], bb[2];
    #pragma unroll
    for (int mi = 0; mi < 4; ++mi)
      a[mi] = *reinterpret_cast<const bf16x8*>(sA + (mi * 16 + lr) * 64 + kk * 32 + lk);
    #pragma unroll
    for (int ni = 0; ni < 2; ++ni)
      bb[ni] = *reinterpret_cast<const bf16x8*>(sB + (w * 32 + ni * 16 + lr) * 64 + kk * 32 + lk);
    #pragma unroll
    for (int mi = 0; mi < 4; ++mi)
      #pragma unroll
      for (int ni = 0; ni < 2; ++ni)
        acc[mi][ni] = __builtin_amdgcn_mfma_f32_16x16x32_bf16(a[mi], bb[ni], acc[mi][ni], 0, 0, 0);
  }
}

// ---------- init GEMM: h0 (into hs[0], stride 1088), m0, xconst += im@Wimg^T ----------
__global__ __launch_bounds__(256) void k_init_gemm(
    const bf16_t* __restrict__ imb,  const bf16_t* __restrict__ fchw,
    const bf16_t* __restrict__ fcmw, const bf16_t* __restrict__ wimg,
    const float* __restrict__ fc_h_b,const float* __restrict__ fc_m_b,
    bf16_t* __restrict__ h0, float* __restrict__ m0, float* __restrict__ xconst){
  __shared__ __align__(16) unsigned char smem[(BM + 128) * LDSP * 2];
  bf16_t* sA = (bf16_t*)smem;
  bf16_t* sB = (bf16_t*)(smem + BM * LDSP * 2);
  int tid = threadIdx.x;
  int cb = blockIdx.x, rb = blockIdx.y;
  int nBase = cb * 128;
  const bf16_t* Bsrc; int nOff;
  if      (nBase < 1024){ Bsrc = fchw; nOff = nBase; }
  else if (nBase < 2048){ Bsrc = fcmw; nOff = nBase - 1024; }
  else                  { Bsrc = wimg; nOff = nBase - 2048; }

  f32x4 acc[4][2] = {};
  int lane = tid & 63, w = tid >> 6;
  for (int kt = 0; kt < 16; ++kt){
    stageA(sA, imb + (size_t)(rb * 64) * 1024 + kt * 64, 1024, tid);
    #pragma unroll
    for (int i = 0; i < 4; ++i){
      int idx = tid + i * 256;
      int r = idx >> 3, v = idx & 7;
      *reinterpret_cast<bf16x8*>(sB + r * LDSP + v * 8) =
        *reinterpret_cast<const bf16x8*>(Bsrc + (size_t)(nOff + r) * 1024 + kt * 64 + v * 8);
    }
    __syncthreads();
    mma_tile(sA, sB, acc, lane, w);
    __syncthreads();
  }
  int lr = lane & 15, lg = lane >> 4;
  #pragma unroll
  for (int mi = 0; mi < 4; ++mi)
    #pragma unroll
    for (int ni = 0; ni < 2; ++ni)
      #pragma unroll
      for (int r = 0; r < 4; ++r){
        int ng   = nBase + w * 32 + ni * 16 + lr;
        int rowg = rb * 64 + mi * 16 + lg * 4 + r;
        float v = acc[mi][ni][r];
        if (ng < 1024){
          h0[(size_t)rowg * HLD + ng] = (bf16_t)tanhf(v + fc_h_b[ng]);
        } else if (ng < 2048){
          int n = ng - 1024;
          m0[(size_t)rowg * 1024 + n] = tanhf(v + fc_m_b[n]);
        } else {
          int n = ng - 2048;
          xconst[(size_t)rowg * 4096 + n] += v;
        }
      }
}

// ---------- per-step fused gates GEMM + LSTM cell ----------
// grid (32, 8): cb = hcol block (32 cols x 4 gates = 128 n-rows), rb = 64-row block.
// K = 1088 (h | label), 17 iters of 64. Staging via global_load_lds width-16.
__global__ __launch_bounds__(256) void k_step(
    const bf16_t* __restrict__ hin,    // hs + t*HSTEP     (rows stride 1088)
    bf16_t* __restrict__ hout,         // hs + (t+1)*HSTEP (writes cols 0..1024)
    const bf16_t* __restrict__ whhx,   // 4096 x 1088
    const float* __restrict__ xconst,  // 512 x 4096
    const float* __restrict__ w_ih,    // begin col 1040
    float* __restrict__ m,             // 512 x 1024 f32
    int t){
  __shared__ __align__(16) unsigned char smem[34816];
  bf16_t* sA = (bf16_t*)smem;           // [64][64] linear (8 KB)
  bf16_t* sB = (bf16_t*)(smem + 8192);  // [128][64] linear (16 KB)
  float*  gbuf = (float*)smem;          // reused post-loop (33792 B)
  int tid = threadIdx.x;
  int cb = blockIdx.x, rb = blockIdx.y;
  int lane = tid & 63, w = tid >> 6;
  int rsub = lane >> 3;                 // 0..7 row-in-chunk
  int c8   = (lane & 7) * 8;            // col element offset
  f32x4 acc[4][2] = {};

  for (int kt = 0; kt < 17; ++kt){
    int kb = kt * 64;
    // A: 8 chunks of 1KB (8 rows each); wave w stages chunks 2w, 2w+1
    #pragma unroll
    for (int c = 0; c < 2; ++c){
      int q = w * 2 + c;
      int r = q * 8 + rsub;
      const bf16_t* g = hin + (size_t)(rb * 64 + r) * HLD + kb + c8;
      __builtin_amdgcn_global_load_lds((const void*)g, (void*)((char*)sA + q * 1024), 16, 0, 0);
    }
    // B: 16 chunks; wave w stages chunks 4w..4w+3
    #pragma unroll
    for (int c = 0; c < 4; ++c){
      int q = w * 4 + c;
      int r = q * 8 + rsub;             // n-local 0..127
      int n = (r >> 5) * 1024 + cb * 32 + (r & 31);
      const bf16_t* g = whhx + (size_t)n * HLD + kb + c8;
      __builtin_amdgcn_global_load_lds((const void*)g, (void*)((char*)sB + q * 1024), 16, 0, 0);
    }
    __syncthreads();
    mma_tile_lin(sA, sB, acc, lane, w);
    __syncthreads();
  }

  // epilogue: xconst (+ begin at t==0), gate exchange via LDS, fused cell
  int lr = lane & 15, lg = lane >> 4;
  #pragma unroll
  for (int mi = 0; mi < 4; ++mi)
    #pragma unroll
    for (int ni = 0; ni < 2; ++ni)
      #pragma unroll
      for (int r = 0; r < 4; ++r){
        int cl = ni * 16 + lr;
        int ng = w * 1024 + cb * 32 + cl;
        int rl = mi * 16 + lg * 4 + r;
        int rowg = rb * 64 + rl;
        float v = acc[mi][ni][r] + xconst[(size_t)rowg * 4096 + ng];
        if (t == 0) v += w_ih[(size_t)ng * DINn + 1040];
        gbuf[(w * 64 + rl) * 33 + cl] = v;
      }
  __syncthreads();
  #pragma unroll
  for (int rep = 0; rep < 8; ++rep){
    int cell = tid + rep * 256;          // 64 rows x 32 cols
    int rl = cell >> 5, cl = cell & 31;
    float gi = gbuf[(0 * 64 + rl) * 33 + cl];
    float gf = gbuf[(1 * 64 + rl) * 33 + cl];
    float gg = gbuf[(2 * 64 + rl) * 33 + cl];
    float go = gbuf[(3 * 64 + rl) * 33 + cl];
    int rowg = rb * 64 + rl, colg = cb * 32 + cl;
    size_t o = (size_t)rowg * 1024 + colg;
    float mo = m[o];
    float mn = sigm(gf) * mo + sigm(gi) * tanhf(gg);
    m[o] = mn;
    float hn = sigm(go) * tanhf(mn);
    hout[(size_t)rowg * HLD + colg] = (bf16_t)hn;
  }
}

// ---------- batched out GEMM + activations + mask + scatter ----------
__global__ __launch_bounds__(256) void k_out(
    const bf16_t* __restrict__ h,      // hs + HSTEP: 24576 rows, stride 1088
    const bf16_t* __restrict__ fcwb,
    const float* __restrict__ fc_b, const int* __restrict__ length,
    float* __restrict__ out){
  __shared__ __align__(16) unsigned char smem[(BM + 128) * LDSP * 2];
  bf16_t* sA = (bf16_t*)smem;
  bf16_t* sB = (bf16_t*)(smem + BM * LDSP * 2);
  int tid = threadIdx.x;
  int cb = blockIdx.x, rb = blockIdx.y;
  f32x4 acc[4][2] = {};
  int lane = tid & 63, w = tid >> 6;
  for (int kt = 0; kt < 16; ++kt){
    stageA(sA, h + (size_t)(rb * 64) * HLD + kt * 64, HLD, tid);
    #pragma unroll
    for (int i = 0; i < 4; ++i){
      int idx = tid + i * 256;
      int r = idx >> 3, v = idx & 7;
      int n = cb * 128 + r;
      bf16x8 val = {};
      if (n < NOn)
        val = *reinterpret_cast<const bf16x8*>(fcwb + (size_t)n * 1024 + kt * 64 + v * 8);
      *reinterpret_cast<bf16x8*>(sB + r * LDSP + v * 8) = val;
    }
    __syncthreads();
    mma_tile(sA, sB, acc, lane, w);
    __syncthreads();
  }
  int lr = lane & 15, lg = lane >> 4;
  #pragma unroll
  for (int mi = 0; mi < 4; ++mi)
    #pragma unroll
    for (int ni = 0; ni < 2; ++ni)
      #pragma unroll
      for (int r = 0; r < 4; ++r){
        int ng = cb * 128 + w * 32 + ni * 16 + lr;
        if (ng >= NOn) continue;
        int rg = rb * 64 + mi * 16 + lg * 4 + r;
        int tt = rg >> 9, b = rg & 511;
        float v = acc[mi][ni][r] + fc_b[ng];
        float mask = (tt < length[b]) ? 1.0f : 0.0f;
        if      (ng < 64)    out[(size_t)rg * 64 + ng] = sigm(v) * mask;
        else if (ng < 1088)  out[(size_t)1572864 + (size_t)rg * 1024 + (ng - 64)] = fmaxf(v, 0.f) * mask;
        else if (ng == 1088) out[(size_t)26738688 + rg] = sigm(v) * mask;
        else                 out[(size_t)26763264 + rg] = __expf(v) * mask;
      }
}

extern "C" void kernel_launch(void* const* d_in, const int* in_sizes, int n_in,
                              void* d_out, int out_size, void* d_ws, size_t ws_size,
                              hipStream_t stream){
  const float* image  = (const float*)d_in[0];
  const float* vp     = (const float*)d_in[1];
  const float* label  = (const float*)d_in[2];
  const int*   length = (const int*)  d_in[3];
  const float* fc_h_w = (const float*)d_in[4];
  const float* fc_h_b = (const float*)d_in[5];
  const float* fc_m_w = (const float*)d_in[6];
  const float* fc_m_b = (const float*)d_in[7];
  const float* w_ih   = (const float*)d_in[8];
  const float* w_hh   = (const float*)d_in[9];
  const float* b_ih   = (const float*)d_in[10];
  const float* b_hh   = (const float*)d_in[11];
  const float* fc_w   = (const float*)d_in[12];
  const float* fc_b   = (const float*)d_in[13];
  float* out = (float*)d_out;

  char* ws = (char*)d_ws;
  bf16_t* imb    = (bf16_t*)(ws + 0);           // 1 MB
  bf16_t* hs     = (bf16_t*)(ws + 1048576);     // 49 x 512 x 1088 bf16 = 54.6 MB
  float*  m      = (float*) (ws + 55640064);    // 2 MB
  float*  xconst = (float*) (ws + 57737216);    // 8 MB
  bf16_t* whhx   = (bf16_t*)(ws + 66125824);    // 4096x1088 = 8.9 MB
  bf16_t* wimgb  = (bf16_t*)(ws + 75038720);    // 8 MB
  bf16_t* fchwb  = (bf16_t*)(ws + 83427328);    // 2 MB
  bf16_t* fcmwb  = (bf16_t*)(ws + 85524480);    // 2 MB
  bf16_t* fcwb   = (bf16_t*)(ws + 87621632);    // 2.2 MB (ends 89853952)

  k_mean   <<<dim3(512),  dim3(256), 0, stream>>>(image, imb);
  k_convert<<<dim3(2048), dim3(256), 0, stream>>>(w_hh, fc_h_w, fc_m_w, fc_w, label, w_ih,
                                                  whhx, fchwb, fcmwb, fcwb, wimgb, hs);
  k_vpc    <<<dim3(8192), dim3(256), 0, stream>>>(w_ih, vp, b_ih, b_hh, xconst);
  k_init_gemm<<<dim3(48, 8), dim3(256), 0, stream>>>(imb, fchwb, fcmwb, wimgb,
                                                     fc_h_b, fc_m_b, hs, m, xconst);
  for (int t = 0; t < Tn; ++t){
    k_step<<<dim3(32, 8), dim3(256), 0, stream>>>(hs + (size_t)t * HSTEP,
                                                  hs + (size_t)(t + 1) * HSTEP,
                                                  whhx, xconst, w_ih, m, t);
  }
  k_out<<<dim3(9, 384), dim3(256), 0, stream>>>(hs + (size_t)HSTEP, fcwb, fc_b, length, out);
}

// Round 11
// 1266.415 us; speedup vs baseline: 2.8892x; 1.0943x over previous
//
#include <hip/hip_runtime.h>
#include <hip/hip_bf16.h>
#include <cstdint>

// ReportDecoder: B=512,S=49,E=1024,H=1024,V2=16,L=64,T=48, D_IN=1105
// Round 11: r10 +
//  (1) k_step: 3-buffer async pipeline — global_load_lds staged 2 iters ahead,
//      counted s_waitcnt vmcnt(12/6/0), RAW s_barrier (no implicit vmcnt(0) drain).
//  (2) k_out: N-tile 256 (grid 5x384) to halve A-panel re-fetch.
// Everything else identical to r10 (concat-K=1088, per-step launches, fused cell).

typedef __bf16 bf16_t;
typedef bf16_t bf16x8 __attribute__((ext_vector_type(8)));
typedef bf16_t bf16x4 __attribute__((ext_vector_type(4)));
typedef float  f32x4  __attribute__((ext_vector_type(4)));

#define Bn    512
#define Sn    49
#define En    1024
#define Hn    1024
#define Ln    64
#define Tn    48
#define DINn  1105
#define NOn   1090
#define HLD   1088          // h row stride (1024 h + 64 label)
#define HSTEP 557056        // 512*1088 elements per step slab

#define BM   64
#define LDSP 72             // padded K-stride for init/out GEMM LDS tiles

__device__ __forceinline__ float sigm(float x){ return 1.0f / (1.0f + __expf(-x)); }

// ---------- image mean ----------
__global__ __launch_bounds__(256) void k_mean(const float* __restrict__ image,
                                              bf16_t* __restrict__ imb){
  int b  = blockIdx.x;
  int e0 = threadIdx.x * 4;
  const float* p = image + (size_t)b * (Sn * En) + e0;
  float4 acc = make_float4(0.f, 0.f, 0.f, 0.f);
  for (int s = 0; s < Sn; ++s){
    float4 v = *reinterpret_cast<const float4*>(p + (size_t)s * En);
    acc.x += v.x; acc.y += v.y; acc.z += v.z; acc.w += v.w;
  }
  const float inv = 1.0f / 49.0f;
  bf16x4 o;
  o[0] = (bf16_t)(acc.x * inv); o[1] = (bf16_t)(acc.y * inv);
  o[2] = (bf16_t)(acc.z * inv); o[3] = (bf16_t)(acc.w * inv);
  *reinterpret_cast<bf16x4*>(imb + (size_t)b * En + e0) = o;
}

// ---------- conversions: whhx concat, fc weights, wimg, label scatter into hs ----------
__global__ __launch_bounds__(256) void k_convert(
    const float* __restrict__ w_hh,  const float* __restrict__ fc_h_w,
    const float* __restrict__ fc_m_w,const float* __restrict__ fc_w,
    const float* __restrict__ label, const float* __restrict__ w_ih,
    bf16_t* __restrict__ whhx,  bf16_t* __restrict__ fchwb,
    bf16_t* __restrict__ fcmwb, bf16_t* __restrict__ fcwb,
    bf16_t* __restrict__ wimgb, bf16_t* __restrict__ hs){
  const int E0 = 4096 * 1088;
  const int E1 = E0 + 1024 * 1024;
  const int E2 = E1 + 1024 * 1024;
  const int E3 = E2 + 1090 * 1024;
  const int E4 = E3 + 4096 * 1024;
  const int E5 = E4 + 48 * 512 * 64;
  int stride = gridDim.x * blockDim.x;
  for (int i = blockIdx.x * blockDim.x + threadIdx.x; i < E5; i += stride){
    if (i < E0){
      int n = i / 1088, k = i - n * 1088;
      float v = (k < 1024) ? w_hh[(size_t)n * 1024 + k]
                           : w_ih[(size_t)n * DINn + 1041 + (k - 1024)];
      whhx[i] = (bf16_t)v;
    } else if (i < E1){ int j = i - E0; fchwb[j] = (bf16_t)fc_h_w[j]; }
    else if (i < E2){ int j = i - E1; fcmwb[j] = (bf16_t)fc_m_w[j]; }
    else if (i < E3){ int j = i - E2; fcwb[j]  = (bf16_t)fc_w[j]; }
    else if (i < E4){
      int j = i - E3; int n = j >> 10, k = j & 1023;
      wimgb[j] = (bf16_t)w_ih[(size_t)n * DINn + k];
    } else {
      int j = i - E4;
      int t = j >> 15, rem = j & 32767, row = rem >> 6, c = rem & 63;
      float v = (t == 0) ? 0.f : label[(size_t)row * (Sn * Ln) + (t - 1) * 64 + c];
      hs[((size_t)t * 512 + row) * HLD + 1024 + c] = (bf16_t)v;
    }
  }
}

// ---------- xconst pre-pass ----------
__global__ __launch_bounds__(256) void k_vpc(const float* __restrict__ w_ih,
                                             const float* __restrict__ vp,
                                             const float* __restrict__ b_ih,
                                             const float* __restrict__ b_hh,
                                             float* __restrict__ xconst){
  int idx = blockIdx.x * 256 + threadIdx.x;
  int b = idx >> 12, n = idx & 4095;
  float acc = b_ih[n] + b_hh[n];
  const float* w = w_ih + (size_t)n * DINn + En;
  const float* v = vp + b * 16;
  #pragma unroll
  for (int j = 0; j < 16; ++j) acc += v[j] * w[j];
  xconst[idx] = acc;
}

// ---------- padded-LDS helpers (init/out GEMMs) ----------
__device__ __forceinline__ void stageA(bf16_t* sA, const bf16_t* gptr, int ld, int tid){
  #pragma unroll
  for (int i = 0; i < 2; ++i){
    int idx = tid + i * 256;
    int r = idx >> 3, v = idx & 7;
    *reinterpret_cast<bf16x8*>(sA + r * LDSP + v * 8) =
      *reinterpret_cast<const bf16x8*>(gptr + (size_t)r * ld + v * 8);
  }
}

__device__ __forceinline__ void mma_tile(const bf16_t* sA, const bf16_t* sB,
                                         f32x4 (&acc)[4][2], int lane, int w){
  int lr = lane & 15;
  int lk = (lane >> 4) * 8;
  #pragma unroll
  for (int kk = 0; kk < 2; ++kk){
    bf16x8 a[4], bb[2];
    #pragma unroll
    for (int mi = 0; mi < 4; ++mi)
      a[mi] = *reinterpret_cast<const bf16x8*>(sA + (mi * 16 + lr) * LDSP + kk * 32 + lk);
    #pragma unroll
    for (int ni = 0; ni < 2; ++ni)
      bb[ni] = *reinterpret_cast<const bf16x8*>(sB + (w * 32 + ni * 16 + lr) * LDSP + kk * 32 + lk);
    #pragma unroll
    for (int mi = 0; mi < 4; ++mi)
      #pragma unroll
      for (int ni = 0; ni < 2; ++ni)
        acc[mi][ni] = __builtin_amdgcn_mfma_f32_16x16x32_bf16(a[mi], bb[ni], acc[mi][ni], 0, 0, 0);
  }
}

// linear-LDS variant for k_step
__device__ __forceinline__ void mma_tile_lin(const bf16_t* sA, const bf16_t* sB,
                                             f32x4 (&acc)[4][2], int lane, int w){
  int lr = lane & 15;
  int lk = (lane >> 4) * 8;
  #pragma unroll
  for (int kk = 0; kk < 2; ++kk){
    bf16x8 a[4], bb[2];
    #pragma unroll
    for (int mi = 0; mi < 4; ++mi)
      a[mi] = *reinterpret_cast<const bf16x8*>(sA + (mi * 16 + lr) * 64 + kk * 32 + lk);
    #pragma unroll
    for (int ni = 0; ni < 2; ++ni)
      bb[ni] = *reinterpret_cast<const bf16x8*>(sB + (w * 32 + ni * 16 + lr) * 64 + kk * 32 + lk);
    #pragma unroll
    for (int mi = 0; mi < 4; ++mi)
      #pragma unroll
      for (int ni = 0; ni < 2; ++ni)
        acc[mi][ni] = __builtin_amdgcn_mfma_f32_16x16x32_bf16(a[mi], bb[ni], acc[mi][ni], 0, 0, 0);
  }
}

// ---------- init GEMM: h0 (stride 1088), m0, xconst += im@Wimg^T ----------
__global__ __launch_bounds__(256) void k_init_gemm(
    const bf16_t* __restrict__ imb,  const bf16_t* __restrict__ fchw,
    const bf16_t* __restrict__ fcmw, const bf16_t* __restrict__ wimg,
    const float* __restrict__ fc_h_b,const float* __restrict__ fc_m_b,
    bf16_t* __restrict__ h0, float* __restrict__ m0, float* __restrict__ xconst){
  __shared__ __align__(16) unsigned char smem[(BM + 128) * LDSP * 2];
  bf16_t* sA = (bf16_t*)smem;
  bf16_t* sB = (bf16_t*)(smem + BM * LDSP * 2);
  int tid = threadIdx.x;
  int cb = blockIdx.x, rb = blockIdx.y;
  int nBase = cb * 128;
  const bf16_t* Bsrc; int nOff;
  if      (nBase < 1024){ Bsrc = fchw; nOff = nBase; }
  else if (nBase < 2048){ Bsrc = fcmw; nOff = nBase - 1024; }
  else                  { Bsrc = wimg; nOff = nBase - 2048; }

  f32x4 acc[4][2] = {};
  int lane = tid & 63, w = tid >> 6;
  for (int kt = 0; kt < 16; ++kt){
    stageA(sA, imb + (size_t)(rb * 64) * 1024 + kt * 64, 1024, tid);
    #pragma unroll
    for (int i = 0; i < 4; ++i){
      int idx = tid + i * 256;
      int r = idx >> 3, v = idx & 7;
      *reinterpret_cast<bf16x8*>(sB + r * LDSP + v * 8) =
        *reinterpret_cast<const bf16x8*>(Bsrc + (size_t)(nOff + r) * 1024 + kt * 64 + v * 8);
    }
    __syncthreads();
    mma_tile(sA, sB, acc, lane, w);
    __syncthreads();
  }
  int lr = lane & 15, lg = lane >> 4;
  #pragma unroll
  for (int mi = 0; mi < 4; ++mi)
    #pragma unroll
    for (int ni = 0; ni < 2; ++ni)
      #pragma unroll
      for (int r = 0; r < 4; ++r){
        int ng   = nBase + w * 32 + ni * 16 + lr;
        int rowg = rb * 64 + mi * 16 + lg * 4 + r;
        float v = acc[mi][ni][r];
        if (ng < 1024){
          h0[(size_t)rowg * HLD + ng] = (bf16_t)tanhf(v + fc_h_b[ng]);
        } else if (ng < 2048){
          int n = ng - 1024;
          m0[(size_t)rowg * 1024 + n] = tanhf(v + fc_m_b[n]);
        } else {
          int n = ng - 2048;
          xconst[(size_t)rowg * 4096 + n] += v;
        }
      }
}

// ---------- per-step fused gates GEMM + LSTM cell (3-buffer async pipeline) ----------
// grid (32, 8). K = 1088 = 17x64. Buffers: 3 x (8KB A + 16KB B) = 72 KB LDS.
// Per iter: stage(kt+2) -> vmcnt(12) [counted] -> raw s_barrier -> MFMA -> raw s_barrier.
__global__ __launch_bounds__(256) void k_step(
    const bf16_t* __restrict__ hin,
    bf16_t* __restrict__ hout,
    const bf16_t* __restrict__ whhx,   // 4096 x 1088
    const float* __restrict__ xconst,  // 512 x 4096
    const float* __restrict__ w_ih,    // begin col 1040
    float* __restrict__ m,             // 512 x 1024 f32
    int t){
  __shared__ __align__(16) unsigned char smem[73728];   // 3 x 24576
  float* gbuf = (float*)smem;                           // reused post-loop
  int tid = threadIdx.x;
  int cb = blockIdx.x, rb = blockIdx.y;
  int lane = tid & 63, w = tid >> 6;
  int rsub = lane >> 3;
  int c8   = (lane & 7) * 8;
  f32x4 acc[4][2] = {};

  auto stage = [&](int buf, int kt){
    int kb = kt * 64;
    char* base = (char*)smem + buf * 24576;
    #pragma unroll
    for (int c = 0; c < 2; ++c){
      int q = w * 2 + c;
      int r = q * 8 + rsub;
      const bf16_t* g = hin + (size_t)(rb * 64 + r) * HLD + kb + c8;
      __builtin_amdgcn_global_load_lds((const void*)g, (void*)(base + q * 1024), 16, 0, 0);
    }
    #pragma unroll
    for (int c = 0; c < 4; ++c){
      int q = w * 4 + c;
      int r = q * 8 + rsub;
      int n = (r >> 5) * 1024 + cb * 32 + (r & 31);
      const bf16_t* g = whhx + (size_t)n * HLD + kb + c8;
      __builtin_amdgcn_global_load_lds((const void*)g, (void*)(base + 8192 + q * 1024), 16, 0, 0);
    }
  };

  stage(0, 0);
  stage(1, 1);
  for (int kt = 0; kt < 15; ++kt){
    stage((kt + 2) % 3, kt + 2);
    asm volatile("s_waitcnt vmcnt(12)" ::: "memory");   // my 6 loads for buf[kt] done
    __builtin_amdgcn_sched_barrier(0);
    __builtin_amdgcn_s_barrier();                        // everyone's buf[kt] done
    bf16_t* cA = (bf16_t*)((char*)smem + (kt % 3) * 24576);
    mma_tile_lin(cA, cA + 4096, acc, lane, w);
    __builtin_amdgcn_s_barrier();                        // WAR guard before re-stage
  }
  // kt = 15 (buf 0)
  asm volatile("s_waitcnt vmcnt(6)" ::: "memory");
  __builtin_amdgcn_sched_barrier(0);
  __builtin_amdgcn_s_barrier();
  {
    bf16_t* cA = (bf16_t*)((char*)smem + 0 * 24576);
    mma_tile_lin(cA, cA + 4096, acc, lane, w);
  }
  __builtin_amdgcn_s_barrier();
  // kt = 16 (buf 1)
  asm volatile("s_waitcnt vmcnt(0)" ::: "memory");
  __builtin_amdgcn_sched_barrier(0);
  __builtin_amdgcn_s_barrier();
  {
    bf16_t* cA = (bf16_t*)((char*)smem + 1 * 24576);
    mma_tile_lin(cA, cA + 4096, acc, lane, w);
  }
  __syncthreads();   // full drain before LDS reuse as gbuf

  // epilogue: xconst (+ begin at t==0), gate exchange via LDS, fused cell
  int lr = lane & 15, lg = lane >> 4;
  #pragma unroll
  for (int mi = 0; mi < 4; ++mi)
    #pragma unroll
    for (int ni = 0; ni < 2; ++ni)
      #pragma unroll
      for (int r = 0; r < 4; ++r){
        int cl = ni * 16 + lr;
        int ng = w * 1024 + cb * 32 + cl;
        int rl = mi * 16 + lg * 4 + r;
        int rowg = rb * 64 + rl;
        float v = acc[mi][ni][r] + xconst[(size_t)rowg * 4096 + ng];
        if (t == 0) v += w_ih[(size_t)ng * DINn + 1040];
        gbuf[(w * 64 + rl) * 33 + cl] = v;
      }
  __syncthreads();
  #pragma unroll
  for (int rep = 0; rep < 8; ++rep){
    int cell = tid + rep * 256;
    int rl = cell >> 5, cl = cell & 31;
    float gi = gbuf[(0 * 64 + rl) * 33 + cl];
    float gf = gbuf[(1 * 64 + rl) * 33 + cl];
    float gg = gbuf[(2 * 64 + rl) * 33 + cl];
    float go = gbuf[(3 * 64 + rl) * 33 + cl];
    int rowg = rb * 64 + rl, colg = cb * 32 + cl;
    size_t o = (size_t)rowg * 1024 + colg;
    float mo = m[o];
    float mn = sigm(gf) * mo + sigm(gi) * tanhf(gg);
    m[o] = mn;
    float hn = sigm(go) * tanhf(mn);
    hout[(size_t)rowg * HLD + colg] = (bf16_t)hn;
  }
}

// ---------- batched out GEMM, N-tile 256 + activations + mask + scatter ----------
__global__ __launch_bounds__(256) void k_out(
    const bf16_t* __restrict__ h,      // hs + HSTEP: 24576 rows, stride 1088
    const bf16_t* __restrict__ fcwb,
    const float* __restrict__ fc_b, const int* __restrict__ length,
    float* __restrict__ out){
  __shared__ __align__(16) unsigned char smem[(BM + 256) * LDSP * 2];
  bf16_t* sA = (bf16_t*)smem;
  bf16_t* sB = (bf16_t*)(smem + BM * LDSP * 2);
  int tid = threadIdx.x;
  int cb = blockIdx.x, rb = blockIdx.y;   // (5, 384)
  f32x4 acc[4][4] = {};
  int lane = tid & 63, w = tid >> 6;
  int lr = lane & 15, lk = (lane >> 4) * 8;
  for (int kt = 0; kt < 16; ++kt){
    stageA(sA, h + (size_t)(rb * 64) * HLD + kt * 64, HLD, tid);
    #pragma unroll
    for (int i = 0; i < 8; ++i){
      int idx = tid + i * 256;
      int r = idx >> 3, v = idx & 7;
      int n = cb * 256 + r;
      bf16x8 val = {};
      if (n < NOn)
        val = *reinterpret_cast<const bf16x8*>(fcwb + (size_t)n * 1024 + kt * 64 + v * 8);
      *reinterpret_cast<bf16x8*>(sB + r * LDSP + v * 8) = val;
    }
    __syncthreads();
    #pragma unroll
    for (int kk = 0; kk < 2; ++kk){
      bf16x8 a[4], bb[4];
      #pragma unroll
      for (int mi = 0; mi < 4; ++mi)
        a[mi] = *reinterpret_cast<const bf16x8*>(sA + (mi * 16 + lr) * LDSP + kk * 32 + lk);
      #pragma unroll
      for (int ni = 0; ni < 4; ++ni)
        bb[ni] = *reinterpret_cast<const bf16x8*>(sB + (w * 64 + ni * 16 + lr) * LDSP + kk * 32 + lk);
      #pragma unroll
      for (int mi = 0; mi < 4; ++mi)
        #pragma unroll
        for (int ni = 0; ni < 4; ++ni)
          acc[mi][ni] = __builtin_amdgcn_mfma_f32_16x16x32_bf16(a[mi], bb[ni], acc[mi][ni], 0, 0, 0);
    }
    __syncthreads();
  }
  int lg = lane >> 4;
  #pragma unroll
  for (int mi = 0; mi < 4; ++mi)
    #pragma unroll
    for (int ni = 0; ni < 4; ++ni)
      #pragma unroll
      for (int r = 0; r < 4; ++r){
        int ng = cb * 256 + w * 64 + ni * 16 + lr;
        if (ng >= NOn) continue;
        int rg = rb * 64 + mi * 16 + lg * 4 + r;
        int tt = rg >> 9, b = rg & 511;
        float v = acc[mi][ni][r] + fc_b[ng];
        float mask = (tt < length[b]) ? 1.0f : 0.0f;
        if      (ng < 64)    out[(size_t)rg * 64 + ng] = sigm(v) * mask;
        else if (ng < 1088)  out[(size_t)1572864 + (size_t)rg * 1024 + (ng - 64)] = fmaxf(v, 0.f) * mask;
        else if (ng == 1088) out[(size_t)26738688 + rg] = sigm(v) * mask;
        else                 out[(size_t)26763264 + rg] = __expf(v) * mask;
      }
}

extern "C" void kernel_launch(void* const* d_in, const int* in_sizes, int n_in,
                              void* d_out, int out_size, void* d_ws, size_t ws_size,
                              hipStream_t stream){
  const float* image  = (const float*)d_in[0];
  const float* vp     = (const float*)d_in[1];
  const float* label  = (const float*)d_in[2];
  const int*   length = (const int*)  d_in[3];
  const float* fc_h_w = (const float*)d_in[4];
  const float* fc_h_b = (const float*)d_in[5];
  const float* fc_m_w = (const float*)d_in[6];
  const float* fc_m_b = (const float*)d_in[7];
  const float* w_ih   = (const float*)d_in[8];
  const float* w_hh   = (const float*)d_in[9];
  const float* b_ih   = (const float*)d_in[10];
  const float* b_hh   = (const float*)d_in[11];
  const float* fc_w   = (const float*)d_in[12];
  const float* fc_b   = (const float*)d_in[13];
  float* out = (float*)d_out;

  char* ws = (char*)d_ws;
  bf16_t* imb    = (bf16_t*)(ws + 0);           // 1 MB
  bf16_t* hs     = (bf16_t*)(ws + 1048576);     // 49 x 512 x 1088 bf16 = 54.6 MB
  float*  m      = (float*) (ws + 55640064);    // 2 MB
  float*  xconst = (float*) (ws + 57737216);    // 8 MB
  bf16_t* whhx   = (bf16_t*)(ws + 66125824);    // 8.9 MB
  bf16_t* wimgb  = (bf16_t*)(ws + 75038720);    // 8 MB
  bf16_t* fchwb  = (bf16_t*)(ws + 83427328);    // 2 MB
  bf16_t* fcmwb  = (bf16_t*)(ws + 85524480);    // 2 MB
  bf16_t* fcwb   = (bf16_t*)(ws + 87621632);    // 2.2 MB (ends 89853952)

  k_mean   <<<dim3(512),  dim3(256), 0, stream>>>(image, imb);
  k_convert<<<dim3(2048), dim3(256), 0, stream>>>(w_hh, fc_h_w, fc_m_w, fc_w, label, w_ih,
                                                  whhx, fchwb, fcmwb, fcwb, wimgb, hs);
  k_vpc    <<<dim3(8192), dim3(256), 0, stream>>>(w_ih, vp, b_ih, b_hh, xconst);
  k_init_gemm<<<dim3(48, 8), dim3(256), 0, stream>>>(imb, fchwb, fcmwb, wimgb,
                                                     fc_h_b, fc_m_b, hs, m, xconst);
  for (int t = 0; t < Tn; ++t){
    k_step<<<dim3(32, 8), dim3(256), 0, stream>>>(hs + (size_t)t * HSTEP,
                                                  hs + (size_t)(t + 1) * HSTEP,
                                                  whhx, xconst, w_ih, m, t);
  }
  k_out<<<dim3(5, 384), dim3(256), 0, stream>>>(hs + (size_t)HSTEP, fcwb, fc_b, length, out);
}

// Round 12
// 1174.334 us; speedup vs baseline: 3.1157x; 1.0784x over previous
//
#include <hip/hip_runtime.h>
#include <hip/hip_bf16.h>
#include <cstdint>

// ReportDecoder: B=512,S=49,E=1024,H=1024,V2=16,L=64,T=48, D_IN=1105
// Round 12:
//  (1) k_out reverted to r10's proven N=128 tile (145us, 47% occ).
//  (2) k_step split to 512 blocks (grid 64x8, N=64/block = 1 gate-column set per
//      wave), 3-buffer async pipeline kept, LDS 48KB -> 2 blocks/CU (2 waves/SIMD
//      TLP). Counted waits vmcnt(8/4/0). Epilogue = r1-style wave=gate exchange.

typedef __bf16 bf16_t;
typedef bf16_t bf16x8 __attribute__((ext_vector_type(8)));
typedef bf16_t bf16x4 __attribute__((ext_vector_type(4)));
typedef float  f32x4  __attribute__((ext_vector_type(4)));

#define Bn    512
#define Sn    49
#define En    1024
#define Hn    1024
#define Ln    64
#define Tn    48
#define DINn  1105
#define NOn   1090
#define HLD   1088          // h row stride (1024 h + 64 label)
#define HSTEP 557056        // 512*1088 elements per step slab

#define BM   64
#define LDSP 72             // padded K-stride for init/out GEMM LDS tiles

__device__ __forceinline__ float sigm(float x){ return 1.0f / (1.0f + __expf(-x)); }

// ---------- image mean ----------
__global__ __launch_bounds__(256) void k_mean(const float* __restrict__ image,
                                              bf16_t* __restrict__ imb){
  int b  = blockIdx.x;
  int e0 = threadIdx.x * 4;
  const float* p = image + (size_t)b * (Sn * En) + e0;
  float4 acc = make_float4(0.f, 0.f, 0.f, 0.f);
  for (int s = 0; s < Sn; ++s){
    float4 v = *reinterpret_cast<const float4*>(p + (size_t)s * En);
    acc.x += v.x; acc.y += v.y; acc.z += v.z; acc.w += v.w;
  }
  const float inv = 1.0f / 49.0f;
  bf16x4 o;
  o[0] = (bf16_t)(acc.x * inv); o[1] = (bf16_t)(acc.y * inv);
  o[2] = (bf16_t)(acc.z * inv); o[3] = (bf16_t)(acc.w * inv);
  *reinterpret_cast<bf16x4*>(imb + (size_t)b * En + e0) = o;
}

// ---------- conversions: whhx concat, fc weights, wimg, label scatter into hs ----------
__global__ __launch_bounds__(256) void k_convert(
    const float* __restrict__ w_hh,  const float* __restrict__ fc_h_w,
    const float* __restrict__ fc_m_w,const float* __restrict__ fc_w,
    const float* __restrict__ label, const float* __restrict__ w_ih,
    bf16_t* __restrict__ whhx,  bf16_t* __restrict__ fchwb,
    bf16_t* __restrict__ fcmwb, bf16_t* __restrict__ fcwb,
    bf16_t* __restrict__ wimgb, bf16_t* __restrict__ hs){
  const int E0 = 4096 * 1088;
  const int E1 = E0 + 1024 * 1024;
  const int E2 = E1 + 1024 * 1024;
  const int E3 = E2 + 1090 * 1024;
  const int E4 = E3 + 4096 * 1024;
  const int E5 = E4 + 48 * 512 * 64;
  int stride = gridDim.x * blockDim.x;
  for (int i = blockIdx.x * blockDim.x + threadIdx.x; i < E5; i += stride){
    if (i < E0){
      int n = i / 1088, k = i - n * 1088;
      float v = (k < 1024) ? w_hh[(size_t)n * 1024 + k]
                           : w_ih[(size_t)n * DINn + 1041 + (k - 1024)];
      whhx[i] = (bf16_t)v;
    } else if (i < E1){ int j = i - E0; fchwb[j] = (bf16_t)fc_h_w[j]; }
    else if (i < E2){ int j = i - E1; fcmwb[j] = (bf16_t)fc_m_w[j]; }
    else if (i < E3){ int j = i - E2; fcwb[j]  = (bf16_t)fc_w[j]; }
    else if (i < E4){
      int j = i - E3; int n = j >> 10, k = j & 1023;
      wimgb[j] = (bf16_t)w_ih[(size_t)n * DINn + k];
    } else {
      int j = i - E4;
      int t = j >> 15, rem = j & 32767, row = rem >> 6, c = rem & 63;
      float v = (t == 0) ? 0.f : label[(size_t)row * (Sn * Ln) + (t - 1) * 64 + c];
      hs[((size_t)t * 512 + row) * HLD + 1024 + c] = (bf16_t)v;
    }
  }
}

// ---------- xconst pre-pass ----------
__global__ __launch_bounds__(256) void k_vpc(const float* __restrict__ w_ih,
                                             const float* __restrict__ vp,
                                             const float* __restrict__ b_ih,
                                             const float* __restrict__ b_hh,
                                             float* __restrict__ xconst){
  int idx = blockIdx.x * 256 + threadIdx.x;
  int b = idx >> 12, n = idx & 4095;
  float acc = b_ih[n] + b_hh[n];
  const float* w = w_ih + (size_t)n * DINn + En;
  const float* v = vp + b * 16;
  #pragma unroll
  for (int j = 0; j < 16; ++j) acc += v[j] * w[j];
  xconst[idx] = acc;
}

// ---------- padded-LDS helpers (init/out GEMMs) ----------
__device__ __forceinline__ void stageA(bf16_t* sA, const bf16_t* gptr, int ld, int tid){
  #pragma unroll
  for (int i = 0; i < 2; ++i){
    int idx = tid + i * 256;
    int r = idx >> 3, v = idx & 7;
    *reinterpret_cast<bf16x8*>(sA + r * LDSP + v * 8) =
      *reinterpret_cast<const bf16x8*>(gptr + (size_t)r * ld + v * 8);
  }
}

__device__ __forceinline__ void mma_tile(const bf16_t* sA, const bf16_t* sB,
                                         f32x4 (&acc)[4][2], int lane, int w){
  int lr = lane & 15;
  int lk = (lane >> 4) * 8;
  #pragma unroll
  for (int kk = 0; kk < 2; ++kk){
    bf16x8 a[4], bb[2];
    #pragma unroll
    for (int mi = 0; mi < 4; ++mi)
      a[mi] = *reinterpret_cast<const bf16x8*>(sA + (mi * 16 + lr) * LDSP + kk * 32 + lk);
    #pragma unroll
    for (int ni = 0; ni < 2; ++ni)
      bb[ni] = *reinterpret_cast<const bf16x8*>(sB + (w * 32 + ni * 16 + lr) * LDSP + kk * 32 + lk);
    #pragma unroll
    for (int mi = 0; mi < 4; ++mi)
      #pragma unroll
      for (int ni = 0; ni < 2; ++ni)
        acc[mi][ni] = __builtin_amdgcn_mfma_f32_16x16x32_bf16(a[mi], bb[ni], acc[mi][ni], 0, 0, 0);
  }
}

// ---------- init GEMM: h0 (stride 1088), m0, xconst += im@Wimg^T ----------
__global__ __launch_bounds__(256) void k_init_gemm(
    const bf16_t* __restrict__ imb,  const bf16_t* __restrict__ fchw,
    const bf16_t* __restrict__ fcmw, const bf16_t* __restrict__ wimg,
    const float* __restrict__ fc_h_b,const float* __restrict__ fc_m_b,
    bf16_t* __restrict__ h0, float* __restrict__ m0, float* __restrict__ xconst){
  __shared__ __align__(16) unsigned char smem[(BM + 128) * LDSP * 2];
  bf16_t* sA = (bf16_t*)smem;
  bf16_t* sB = (bf16_t*)(smem + BM * LDSP * 2);
  int tid = threadIdx.x;
  int cb = blockIdx.x, rb = blockIdx.y;
  int nBase = cb * 128;
  const bf16_t* Bsrc; int nOff;
  if      (nBase < 1024){ Bsrc = fchw; nOff = nBase; }
  else if (nBase < 2048){ Bsrc = fcmw; nOff = nBase - 1024; }
  else                  { Bsrc = wimg; nOff = nBase - 2048; }

  f32x4 acc[4][2] = {};
  int lane = tid & 63, w = tid >> 6;
  for (int kt = 0; kt < 16; ++kt){
    stageA(sA, imb + (size_t)(rb * 64) * 1024 + kt * 64, 1024, tid);
    #pragma unroll
    for (int i = 0; i < 4; ++i){
      int idx = tid + i * 256;
      int r = idx >> 3, v = idx & 7;
      *reinterpret_cast<bf16x8*>(sB + r * LDSP + v * 8) =
        *reinterpret_cast<const bf16x8*>(Bsrc + (size_t)(nOff + r) * 1024 + kt * 64 + v * 8);
    }
    __syncthreads();
    mma_tile(sA, sB, acc, lane, w);
    __syncthreads();
  }
  int lr = lane & 15, lg = lane >> 4;
  #pragma unroll
  for (int mi = 0; mi < 4; ++mi)
    #pragma unroll
    for (int ni = 0; ni < 2; ++ni)
      #pragma unroll
      for (int r = 0; r < 4; ++r){
        int ng   = nBase + w * 32 + ni * 16 + lr;
        int rowg = rb * 64 + mi * 16 + lg * 4 + r;
        float v = acc[mi][ni][r];
        if (ng < 1024){
          h0[(size_t)rowg * HLD + ng] = (bf16_t)tanhf(v + fc_h_b[ng]);
        } else if (ng < 2048){
          int n = ng - 1024;
          m0[(size_t)rowg * 1024 + n] = tanhf(v + fc_m_b[n]);
        } else {
          int n = ng - 2048;
          xconst[(size_t)rowg * 4096 + n] += v;
        }
      }
}

// ---------- per-step fused gates GEMM + LSTM cell ----------
// grid (64, 8), 512 blocks = 2 blocks/CU. Block: 64 rows x 64 n (wave w = gate w,
// 16 hcols). 3-buffer async pipeline: stage(kt+2) -> vmcnt(8) -> raw barrier ->
// 8 MFMA -> raw barrier. LDS 48KB (3 x 16KB).
__global__ __launch_bounds__(256, 2) void k_step(
    const bf16_t* __restrict__ hin,
    bf16_t* __restrict__ hout,
    const bf16_t* __restrict__ whhx,   // 4096 x 1088
    const float* __restrict__ xconst,  // 512 x 4096
    const float* __restrict__ w_ih,    // begin col 1040
    float* __restrict__ m,             // 512 x 1024 f32
    int t){
  __shared__ __align__(16) unsigned char smem[49152];   // 3 x 16384
  float* gbuf = (float*)smem;                           // reused post-loop
  int tid = threadIdx.x;
  int cb = blockIdx.x, rb = blockIdx.y;
  int lane = tid & 63, w = tid >> 6;
  int rsub = lane >> 3;
  int c8   = (lane & 7) * 8;
  f32x4 acc[4] = {};

  auto stage = [&](int buf, int kt){
    int kb = kt * 64;
    char* base = (char*)smem + buf * 16384;
    #pragma unroll
    for (int c = 0; c < 2; ++c){
      int q = w * 2 + c;
      int r = q * 8 + rsub;                       // A row 0..63
      const bf16_t* g = hin + (size_t)(rb * 64 + r) * HLD + kb + c8;
      __builtin_amdgcn_global_load_lds((const void*)g, (void*)(base + q * 1024), 16, 0, 0);
    }
    #pragma unroll
    for (int c = 0; c < 2; ++c){
      int q = w * 2 + c;
      int r = q * 8 + rsub;                       // n-local 0..63
      int n = (r >> 4) * 1024 + cb * 16 + (r & 15);
      const bf16_t* g = whhx + (size_t)n * HLD + kb + c8;
      __builtin_amdgcn_global_load_lds((const void*)g, (void*)(base + 8192 + q * 1024), 16, 0, 0);
    }
  };

  int lr = lane & 15, lk = (lane >> 4) * 8;
  auto compute = [&](int buf){
    bf16_t* sA = (bf16_t*)((char*)smem + buf * 16384);
    bf16_t* sB = sA + 4096;
    #pragma unroll
    for (int kk = 0; kk < 2; ++kk){
      bf16x8 a[4], bb;
      #pragma unroll
      for (int mi = 0; mi < 4; ++mi)
        a[mi] = *reinterpret_cast<const bf16x8*>(sA + (mi * 16 + lr) * 64 + kk * 32 + lk);
      bb = *reinterpret_cast<const bf16x8*>(sB + (w * 16 + lr) * 64 + kk * 32 + lk);
      #pragma unroll
      for (int mi = 0; mi < 4; ++mi)
        acc[mi] = __builtin_amdgcn_mfma_f32_16x16x32_bf16(a[mi], bb, acc[mi], 0, 0, 0);
    }
  };

  stage(0, 0);
  stage(1, 1);
  for (int kt = 0; kt < 15; ++kt){
    stage((kt + 2) % 3, kt + 2);
    asm volatile("s_waitcnt vmcnt(8)" ::: "memory");   // my 4 loads for buf[kt] done
    __builtin_amdgcn_sched_barrier(0);
    __builtin_amdgcn_s_barrier();                       // everyone's buf[kt] done
    compute(kt % 3);
    __builtin_amdgcn_s_barrier();                       // WAR guard before re-stage
  }
  asm volatile("s_waitcnt vmcnt(4)" ::: "memory");
  __builtin_amdgcn_sched_barrier(0);
  __builtin_amdgcn_s_barrier();
  compute(0);                                           // kt = 15
  __builtin_amdgcn_s_barrier();
  asm volatile("s_waitcnt vmcnt(0)" ::: "memory");
  __builtin_amdgcn_sched_barrier(0);
  __builtin_amdgcn_s_barrier();
  compute(1);                                           // kt = 16
  __syncthreads();   // full drain before LDS reuse as gbuf

  // epilogue: xconst (+ begin at t==0), wave=gate exchange via LDS, fused cell
  int lg = lane >> 4;
  #pragma unroll
  for (int mi = 0; mi < 4; ++mi)
    #pragma unroll
    for (int r = 0; r < 4; ++r){
      int cl = lr;                       // 0..15
      int ng = w * 1024 + cb * 16 + cl;
      int rl = mi * 16 + lg * 4 + r;
      int rowg = rb * 64 + rl;
      float v = acc[mi][r] + xconst[(size_t)rowg * 4096 + ng];
      if (t == 0) v += w_ih[(size_t)ng * DINn + 1040];
      gbuf[(w * 64 + rl) * 17 + cl] = v;
    }
  __syncthreads();
  #pragma unroll
  for (int rep = 0; rep < 4; ++rep){
    int cell = tid + rep * 256;          // 64 rows x 16 cols
    int rl = cell >> 4, cl = cell & 15;
    float gi = gbuf[(0 * 64 + rl) * 17 + cl];
    float gf = gbuf[(1 * 64 + rl) * 17 + cl];
    float gg = gbuf[(2 * 64 + rl) * 17 + cl];
    float go = gbuf[(3 * 64 + rl) * 17 + cl];
    int rowg = rb * 64 + rl, colg = cb * 16 + cl;
    size_t o = (size_t)rowg * 1024 + colg;
    float mo = m[o];
    float mn = sigm(gf) * mo + sigm(gi) * tanhf(gg);
    m[o] = mn;
    float hn = sigm(go) * tanhf(mn);
    hout[(size_t)rowg * HLD + colg] = (bf16_t)hn;
  }
}

// ---------- batched out GEMM (r10 proven shape) ----------
__global__ __launch_bounds__(256) void k_out(
    const bf16_t* __restrict__ h,      // hs + HSTEP: 24576 rows, stride 1088
    const bf16_t* __restrict__ fcwb,
    const float* __restrict__ fc_b, const int* __restrict__ length,
    float* __restrict__ out){
  __shared__ __align__(16) unsigned char smem[(BM + 128) * LDSP * 2];
  bf16_t* sA = (bf16_t*)smem;
  bf16_t* sB = (bf16_t*)(smem + BM * LDSP * 2);
  int tid = threadIdx.x;
  int cb = blockIdx.x, rb = blockIdx.y;
  f32x4 acc[4][2] = {};
  int lane = tid & 63, w = tid >> 6;
  for (int kt = 0; kt < 16; ++kt){
    stageA(sA, h + (size_t)(rb * 64) * HLD + kt * 64, HLD, tid);
    #pragma unroll
    for (int i = 0; i < 4; ++i){
      int idx = tid + i * 256;
      int r = idx >> 3, v = idx & 7;
      int n = cb * 128 + r;
      bf16x8 val = {};
      if (n < NOn)
        val = *reinterpret_cast<const bf16x8*>(fcwb + (size_t)n * 1024 + kt * 64 + v * 8);
      *reinterpret_cast<bf16x8*>(sB + r * LDSP + v * 8) = val;
    }
    __syncthreads();
    mma_tile(sA, sB, acc, lane, w);
    __syncthreads();
  }
  int lr = lane & 15, lg = lane >> 4;
  #pragma unroll
  for (int mi = 0; mi < 4; ++mi)
    #pragma unroll
    for (int ni = 0; ni < 2; ++ni)
      #pragma unroll
      for (int r = 0; r < 4; ++r){
        int ng = cb * 128 + w * 32 + ni * 16 + lr;
        if (ng >= NOn) continue;
        int rg = rb * 64 + mi * 16 + lg * 4 + r;
        int tt = rg >> 9, b = rg & 511;
        float v = acc[mi][ni][r] + fc_b[ng];
        float mask = (tt < length[b]) ? 1.0f : 0.0f;
        if      (ng < 64)    out[(size_t)rg * 64 + ng] = sigm(v) * mask;
        else if (ng < 1088)  out[(size_t)1572864 + (size_t)rg * 1024 + (ng - 64)] = fmaxf(v, 0.f) * mask;
        else if (ng == 1088) out[(size_t)26738688 + rg] = sigm(v) * mask;
        else                 out[(size_t)26763264 + rg] = __expf(v) * mask;
      }
}

extern "C" void kernel_launch(void* const* d_in, const int* in_sizes, int n_in,
                              void* d_out, int out_size, void* d_ws, size_t ws_size,
                              hipStream_t stream){
  const float* image  = (const float*)d_in[0];
  const float* vp     = (const float*)d_in[1];
  const float* label  = (const float*)d_in[2];
  const int*   length = (const int*)  d_in[3];
  const float* fc_h_w = (const float*)d_in[4];
  const float* fc_h_b = (const float*)d_in[5];
  const float* fc_m_w = (const float*)d_in[6];
  const float* fc_m_b = (const float*)d_in[7];
  const float* w_ih   = (const float*)d_in[8];
  const float* w_hh   = (const float*)d_in[9];
  const float* b_ih   = (const float*)d_in[10];
  const float* b_hh   = (const float*)d_in[11];
  const float* fc_w   = (const float*)d_in[12];
  const float* fc_b   = (const float*)d_in[13];
  float* out = (float*)d_out;

  char* ws = (char*)d_ws;
  bf16_t* imb    = (bf16_t*)(ws + 0);           // 1 MB
  bf16_t* hs     = (bf16_t*)(ws + 1048576);     // 49 x 512 x 1088 bf16 = 54.6 MB
  float*  m      = (float*) (ws + 55640064);    // 2 MB
  float*  xconst = (float*) (ws + 57737216);    // 8 MB
  bf16_t* whhx   = (bf16_t*)(ws + 66125824);    // 8.9 MB
  bf16_t* wimgb  = (bf16_t*)(ws + 75038720);    // 8 MB
  bf16_t* fchwb  = (bf16_t*)(ws + 83427328);    // 2 MB
  bf16_t* fcmwb  = (bf16_t*)(ws + 85524480);    // 2 MB
  bf16_t* fcwb   = (bf16_t*)(ws + 87621632);    // 2.2 MB (ends 89853952)

  k_mean   <<<dim3(512),  dim3(256), 0, stream>>>(image, imb);
  k_convert<<<dim3(2048), dim3(256), 0, stream>>>(w_hh, fc_h_w, fc_m_w, fc_w, label, w_ih,
                                                  whhx, fchwb, fcmwb, fcwb, wimgb, hs);
  k_vpc    <<<dim3(8192), dim3(256), 0, stream>>>(w_ih, vp, b_ih, b_hh, xconst);
  k_init_gemm<<<dim3(48, 8), dim3(256), 0, stream>>>(imb, fchwb, fcmwb, wimgb,
                                                     fc_h_b, fc_m_b, hs, m, xconst);
  for (int t = 0; t < Tn; ++t){
    k_step<<<dim3(64, 8), dim3(256), 0, stream>>>(hs + (size_t)t * HSTEP,
                                                  hs + (size_t)(t + 1) * HSTEP,
                                                  whhx, xconst, w_ih, m, t);
  }
  k_out<<<dim3(9, 384), dim3(256), 0, stream>>>(hs + (size_t)HSTEP, fcwb, fc_b, length, out);
}

// Round 13
// 1121.879 us; speedup vs baseline: 3.2614x; 1.0468x over previous
//
#include <hip/hip_runtime.h>
#include <hip/hip_bf16.h>
#include <cstdint>

// ReportDecoder: B=512,S=49,E=1024,H=1024,V2=16,L=64,T=48, D_IN=1105
// Round 13:
//  (1) k_step: r11's 64x128 block (grid 32x8) with 5-buffer depth-4 async pipeline
//      (120KB LDS): steady vmcnt(24), tail 18/12/6/0. Covers cross-XCD h latency.
//  (2) k_out: N=128 proven shape + XCD A-locality swizzle — all 9 same-A blocks
//      consecutive on one XCD (A fetched once from HBM, 8x L2 hits).

typedef __bf16 bf16_t;
typedef bf16_t bf16x8 __attribute__((ext_vector_type(8)));
typedef bf16_t bf16x4 __attribute__((ext_vector_type(4)));
typedef float  f32x4  __attribute__((ext_vector_type(4)));

#define Bn    512
#define Sn    49
#define En    1024
#define Hn    1024
#define Ln    64
#define Tn    48
#define DINn  1105
#define NOn   1090
#define HLD   1088          // h row stride (1024 h + 64 label)
#define HSTEP 557056        // 512*1088 elements per step slab

#define BM   64
#define LDSP 72             // padded K-stride for init/out GEMM LDS tiles

__device__ __forceinline__ float sigm(float x){ return 1.0f / (1.0f + __expf(-x)); }

// ---------- image mean ----------
__global__ __launch_bounds__(256) void k_mean(const float* __restrict__ image,
                                              bf16_t* __restrict__ imb){
  int b  = blockIdx.x;
  int e0 = threadIdx.x * 4;
  const float* p = image + (size_t)b * (Sn * En) + e0;
  float4 acc = make_float4(0.f, 0.f, 0.f, 0.f);
  for (int s = 0; s < Sn; ++s){
    float4 v = *reinterpret_cast<const float4*>(p + (size_t)s * En);
    acc.x += v.x; acc.y += v.y; acc.z += v.z; acc.w += v.w;
  }
  const float inv = 1.0f / 49.0f;
  bf16x4 o;
  o[0] = (bf16_t)(acc.x * inv); o[1] = (bf16_t)(acc.y * inv);
  o[2] = (bf16_t)(acc.z * inv); o[3] = (bf16_t)(acc.w * inv);
  *reinterpret_cast<bf16x4*>(imb + (size_t)b * En + e0) = o;
}

// ---------- conversions: whhx concat, fc weights, wimg, label scatter into hs ----------
__global__ __launch_bounds__(256) void k_convert(
    const float* __restrict__ w_hh,  const float* __restrict__ fc_h_w,
    const float* __restrict__ fc_m_w,const float* __restrict__ fc_w,
    const float* __restrict__ label, const float* __restrict__ w_ih,
    bf16_t* __restrict__ whhx,  bf16_t* __restrict__ fchwb,
    bf16_t* __restrict__ fcmwb, bf16_t* __restrict__ fcwb,
    bf16_t* __restrict__ wimgb, bf16_t* __restrict__ hs){
  const int E0 = 4096 * 1088;
  const int E1 = E0 + 1024 * 1024;
  const int E2 = E1 + 1024 * 1024;
  const int E3 = E2 + 1090 * 1024;
  const int E4 = E3 + 4096 * 1024;
  const int E5 = E4 + 48 * 512 * 64;
  int stride = gridDim.x * blockDim.x;
  for (int i = blockIdx.x * blockDim.x + threadIdx.x; i < E5; i += stride){
    if (i < E0){
      int n = i / 1088, k = i - n * 1088;
      float v = (k < 1024) ? w_hh[(size_t)n * 1024 + k]
                           : w_ih[(size_t)n * DINn + 1041 + (k - 1024)];
      whhx[i] = (bf16_t)v;
    } else if (i < E1){ int j = i - E0; fchwb[j] = (bf16_t)fc_h_w[j]; }
    else if (i < E2){ int j = i - E1; fcmwb[j] = (bf16_t)fc_m_w[j]; }
    else if (i < E3){ int j = i - E2; fcwb[j]  = (bf16_t)fc_w[j]; }
    else if (i < E4){
      int j = i - E3; int n = j >> 10, k = j & 1023;
      wimgb[j] = (bf16_t)w_ih[(size_t)n * DINn + k];
    } else {
      int j = i - E4;
      int t = j >> 15, rem = j & 32767, row = rem >> 6, c = rem & 63;
      float v = (t == 0) ? 0.f : label[(size_t)row * (Sn * Ln) + (t - 1) * 64 + c];
      hs[((size_t)t * 512 + row) * HLD + 1024 + c] = (bf16_t)v;
    }
  }
}

// ---------- xconst pre-pass ----------
__global__ __launch_bounds__(256) void k_vpc(const float* __restrict__ w_ih,
                                             const float* __restrict__ vp,
                                             const float* __restrict__ b_ih,
                                             const float* __restrict__ b_hh,
                                             float* __restrict__ xconst){
  int idx = blockIdx.x * 256 + threadIdx.x;
  int b = idx >> 12, n = idx & 4095;
  float acc = b_ih[n] + b_hh[n];
  const float* w = w_ih + (size_t)n * DINn + En;
  const float* v = vp + b * 16;
  #pragma unroll
  for (int j = 0; j < 16; ++j) acc += v[j] * w[j];
  xconst[idx] = acc;
}

// ---------- padded-LDS helpers (init/out GEMMs) ----------
__device__ __forceinline__ void stageA(bf16_t* sA, const bf16_t* gptr, int ld, int tid){
  #pragma unroll
  for (int i = 0; i < 2; ++i){
    int idx = tid + i * 256;
    int r = idx >> 3, v = idx & 7;
    *reinterpret_cast<bf16x8*>(sA + r * LDSP + v * 8) =
      *reinterpret_cast<const bf16x8*>(gptr + (size_t)r * ld + v * 8);
  }
}

__device__ __forceinline__ void mma_tile(const bf16_t* sA, const bf16_t* sB,
                                         f32x4 (&acc)[4][2], int lane, int w){
  int lr = lane & 15;
  int lk = (lane >> 4) * 8;
  #pragma unroll
  for (int kk = 0; kk < 2; ++kk){
    bf16x8 a[4], bb[2];
    #pragma unroll
    for (int mi = 0; mi < 4; ++mi)
      a[mi] = *reinterpret_cast<const bf16x8*>(sA + (mi * 16 + lr) * LDSP + kk * 32 + lk);
    #pragma unroll
    for (int ni = 0; ni < 2; ++ni)
      bb[ni] = *reinterpret_cast<const bf16x8*>(sB + (w * 32 + ni * 16 + lr) * LDSP + kk * 32 + lk);
    #pragma unroll
    for (int mi = 0; mi < 4; ++mi)
      #pragma unroll
      for (int ni = 0; ni < 2; ++ni)
        acc[mi][ni] = __builtin_amdgcn_mfma_f32_16x16x32_bf16(a[mi], bb[ni], acc[mi][ni], 0, 0, 0);
  }
}

// linear-LDS variant for k_step
__device__ __forceinline__ void mma_tile_lin(const bf16_t* sA, const bf16_t* sB,
                                             f32x4 (&acc)[4][2], int lane, int w){
  int lr = lane & 15;
  int lk = (lane >> 4) * 8;
  #pragma unroll
  for (int kk = 0; kk < 2; ++kk){
    bf16x8 a[4], bb[2];
    #pragma unroll
    for (int mi = 0; mi < 4; ++mi)
      a[mi] = *reinterpret_cast<const bf16x8*>(sA + (mi * 16 + lr) * 64 + kk * 32 + lk);
    #pragma unroll
    for (int ni = 0; ni < 2; ++ni)
      bb[ni] = *reinterpret_cast<const bf16x8*>(sB + (w * 32 + ni * 16 + lr) * 64 + kk * 32 + lk);
    #pragma unroll
    for (int mi = 0; mi < 4; ++mi)
      #pragma unroll
      for (int ni = 0; ni < 2; ++ni)
        acc[mi][ni] = __builtin_amdgcn_mfma_f32_16x16x32_bf16(a[mi], bb[ni], acc[mi][ni], 0, 0, 0);
  }
}

// ---------- init GEMM: h0 (stride 1088), m0, xconst += im@Wimg^T ----------
__global__ __launch_bounds__(256) void k_init_gemm(
    const bf16_t* __restrict__ imb,  const bf16_t* __restrict__ fchw,
    const bf16_t* __restrict__ fcmw, const bf16_t* __restrict__ wimg,
    const float* __restrict__ fc_h_b,const float* __restrict__ fc_m_b,
    bf16_t* __restrict__ h0, float* __restrict__ m0, float* __restrict__ xconst){
  __shared__ __align__(16) unsigned char smem[(BM + 128) * LDSP * 2];
  bf16_t* sA = (bf16_t*)smem;
  bf16_t* sB = (bf16_t*)(smem + BM * LDSP * 2);
  int tid = threadIdx.x;
  int cb = blockIdx.x, rb = blockIdx.y;
  int nBase = cb * 128;
  const bf16_t* Bsrc; int nOff;
  if      (nBase < 1024){ Bsrc = fchw; nOff = nBase; }
  else if (nBase < 2048){ Bsrc = fcmw; nOff = nBase - 1024; }
  else                  { Bsrc = wimg; nOff = nBase - 2048; }

  f32x4 acc[4][2] = {};
  int lane = tid & 63, w = tid >> 6;
  for (int kt = 0; kt < 16; ++kt){
    stageA(sA, imb + (size_t)(rb * 64) * 1024 + kt * 64, 1024, tid);
    #pragma unroll
    for (int i = 0; i < 4; ++i){
      int idx = tid + i * 256;
      int r = idx >> 3, v = idx & 7;
      *reinterpret_cast<bf16x8*>(sB + r * LDSP + v * 8) =
        *reinterpret_cast<const bf16x8*>(Bsrc + (size_t)(nOff + r) * 1024 + kt * 64 + v * 8);
    }
    __syncthreads();
    mma_tile(sA, sB, acc, lane, w);
    __syncthreads();
  }
  int lr = lane & 15, lg = lane >> 4;
  #pragma unroll
  for (int mi = 0; mi < 4; ++mi)
    #pragma unroll
    for (int ni = 0; ni < 2; ++ni)
      #pragma unroll
      for (int r = 0; r < 4; ++r){
        int ng   = nBase + w * 32 + ni * 16 + lr;
        int rowg = rb * 64 + mi * 16 + lg * 4 + r;
        float v = acc[mi][ni][r];
        if (ng < 1024){
          h0[(size_t)rowg * HLD + ng] = (bf16_t)tanhf(v + fc_h_b[ng]);
        } else if (ng < 2048){
          int n = ng - 1024;
          m0[(size_t)rowg * 1024 + n] = tanhf(v + fc_m_b[n]);
        } else {
          int n = ng - 2048;
          xconst[(size_t)rowg * 4096 + n] += v;
        }
      }
}

// ---------- per-step fused gates GEMM + LSTM cell (5-buffer depth-4 pipeline) ----------
// grid (32, 8). K = 1088 = 17x64. Buffers: 5 x (8KB A + 16KB B) = 120 KB LDS.
// Per iter: stage(kt+4) -> vmcnt(24) [counted] -> raw s_barrier -> MFMA -> raw s_barrier.
__global__ __launch_bounds__(256) void k_step(
    const bf16_t* __restrict__ hin,
    bf16_t* __restrict__ hout,
    const bf16_t* __restrict__ whhx,   // 4096 x 1088
    const float* __restrict__ xconst,  // 512 x 4096
    const float* __restrict__ w_ih,    // begin col 1040
    float* __restrict__ m,             // 512 x 1024 f32
    int t){
  __shared__ __align__(16) unsigned char smem[122880];  // 5 x 24576
  float* gbuf = (float*)smem;                           // reused post-loop
  int tid = threadIdx.x;
  int cb = blockIdx.x, rb = blockIdx.y;
  int lane = tid & 63, w = tid >> 6;
  int rsub = lane >> 3;
  int c8   = (lane & 7) * 8;
  f32x4 acc[4][2] = {};

  auto stage = [&](int buf, int kt){
    int kb = kt * 64;
    char* base = (char*)smem + buf * 24576;
    #pragma unroll
    for (int c = 0; c < 2; ++c){
      int q = w * 2 + c;
      int r = q * 8 + rsub;
      const bf16_t* g = hin + (size_t)(rb * 64 + r) * HLD + kb + c8;
      __builtin_amdgcn_global_load_lds((const void*)g, (void*)(base + q * 1024), 16, 0, 0);
    }
    #pragma unroll
    for (int c = 0; c < 4; ++c){
      int q = w * 4 + c;
      int r = q * 8 + rsub;
      int n = (r >> 5) * 1024 + cb * 32 + (r & 31);
      const bf16_t* g = whhx + (size_t)n * HLD + kb + c8;
      __builtin_amdgcn_global_load_lds((const void*)g, (void*)(base + 8192 + q * 1024), 16, 0, 0);
    }
  };

  stage(0, 0);
  stage(1, 1);
  stage(2, 2);
  stage(3, 3);
  for (int kt = 0; kt < 13; ++kt){
    stage((kt + 4) % 5, kt + 4);
    asm volatile("s_waitcnt vmcnt(24)" ::: "memory");   // my 6 loads for buf[kt] done
    __builtin_amdgcn_sched_barrier(0);
    __builtin_amdgcn_s_barrier();                        // everyone's buf[kt] done
    bf16_t* cA = (bf16_t*)((char*)smem + (kt % 5) * 24576);
    mma_tile_lin(cA, cA + 4096, acc, lane, w);
    __builtin_amdgcn_s_barrier();                        // WAR guard before re-stage
  }
  // kt = 13..16 tail (no more stages; drain 18/12/6/0)
  asm volatile("s_waitcnt vmcnt(18)" ::: "memory");
  __builtin_amdgcn_sched_barrier(0);
  __builtin_amdgcn_s_barrier();
  { bf16_t* cA = (bf16_t*)((char*)smem + (13 % 5) * 24576);
    mma_tile_lin(cA, cA + 4096, acc, lane, w); }
  __builtin_amdgcn_s_barrier();
  asm volatile("s_waitcnt vmcnt(12)" ::: "memory");
  __builtin_amdgcn_sched_barrier(0);
  __builtin_amdgcn_s_barrier();
  { bf16_t* cA = (bf16_t*)((char*)smem + (14 % 5) * 24576);
    mma_tile_lin(cA, cA + 4096, acc, lane, w); }
  __builtin_amdgcn_s_barrier();
  asm volatile("s_waitcnt vmcnt(6)" ::: "memory");
  __builtin_amdgcn_sched_barrier(0);
  __builtin_amdgcn_s_barrier();
  { bf16_t* cA = (bf16_t*)((char*)smem + (15 % 5) * 24576);
    mma_tile_lin(cA, cA + 4096, acc, lane, w); }
  __builtin_amdgcn_s_barrier();
  asm volatile("s_waitcnt vmcnt(0)" ::: "memory");
  __builtin_amdgcn_sched_barrier(0);
  __builtin_amdgcn_s_barrier();
  { bf16_t* cA = (bf16_t*)((char*)smem + (16 % 5) * 24576);
    mma_tile_lin(cA, cA + 4096, acc, lane, w); }
  __syncthreads();   // full drain before LDS reuse as gbuf

  // epilogue: xconst (+ begin at t==0), gate exchange via LDS, fused cell
  int lr = lane & 15, lg = lane >> 4;
  #pragma unroll
  for (int mi = 0; mi < 4; ++mi)
    #pragma unroll
    for (int ni = 0; ni < 2; ++ni)
      #pragma unroll
      for (int r = 0; r < 4; ++r){
        int cl = ni * 16 + lr;
        int ng = w * 1024 + cb * 32 + cl;
        int rl = mi * 16 + lg * 4 + r;
        int rowg = rb * 64 + rl;
        float v = acc[mi][ni][r] + xconst[(size_t)rowg * 4096 + ng];
        if (t == 0) v += w_ih[(size_t)ng * DINn + 1040];
        gbuf[(w * 64 + rl) * 33 + cl] = v;
      }
  __syncthreads();
  #pragma unroll
  for (int rep = 0; rep < 8; ++rep){
    int cell = tid + rep * 256;
    int rl = cell >> 5, cl = cell & 31;
    float gi = gbuf[(0 * 64 + rl) * 33 + cl];
    float gf = gbuf[(1 * 64 + rl) * 33 + cl];
    float gg = gbuf[(2 * 64 + rl) * 33 + cl];
    float go = gbuf[(3 * 64 + rl) * 33 + cl];
    int rowg = rb * 64 + rl, colg = cb * 32 + cl;
    size_t o = (size_t)rowg * 1024 + colg;
    float mo = m[o];
    float mn = sigm(gf) * mo + sigm(gi) * tanhf(gg);
    m[o] = mn;
    float hn = sigm(go) * tanhf(mn);
    hout[(size_t)rowg * HLD + colg] = (bf16_t)hn;
  }
}

// ---------- batched out GEMM (N=128) + XCD A-locality swizzle ----------
// 1D grid 3456: id = xcd + 8*(cb + 9*grp); rb = xcd + 8*grp.
// The 9 same-A blocks are consecutive on one XCD -> A fetched once, 8x L2 hits.
__global__ __launch_bounds__(256) void k_out(
    const bf16_t* __restrict__ h,      // hs + HSTEP: 24576 rows, stride 1088
    const bf16_t* __restrict__ fcwb,
    const float* __restrict__ fc_b, const int* __restrict__ length,
    float* __restrict__ out){
  __shared__ __align__(16) unsigned char smem[(BM + 128) * LDSP * 2];
  bf16_t* sA = (bf16_t*)smem;
  bf16_t* sB = (bf16_t*)(smem + BM * LDSP * 2);
  int tid = threadIdx.x;
  int id  = blockIdx.x;
  int xcd = id & 7;
  int rem = id >> 3;
  int cb  = rem % 9;
  int grp = rem / 9;
  int rb  = xcd + 8 * grp;               // 0..383
  f32x4 acc[4][2] = {};
  int lane = tid & 63, w = tid >> 6;
  for (int kt = 0; kt < 16; ++kt){
    stageA(sA, h + (size_t)(rb * 64) * HLD + kt * 64, HLD, tid);
    #pragma unroll
    for (int i = 0; i < 4; ++i){
      int idx = tid + i * 256;
      int r = idx >> 3, v = idx & 7;
      int n = cb * 128 + r;
      bf16x8 val = {};
      if (n < NOn)
        val = *reinterpret_cast<const bf16x8*>(fcwb + (size_t)n * 1024 + kt * 64 + v * 8);
      *reinterpret_cast<bf16x8*>(sB + r * LDSP + v * 8) = val;
    }
    __syncthreads();
    mma_tile(sA, sB, acc, lane, w);
    __syncthreads();
  }
  int lr = lane & 15, lg = lane >> 4;
  #pragma unroll
  for (int mi = 0; mi < 4; ++mi)
    #pragma unroll
    for (int ni = 0; ni < 2; ++ni)
      #pragma unroll
      for (int r = 0; r < 4; ++r){
        int ng = cb * 128 + w * 32 + ni * 16 + lr;
        if (ng >= NOn) continue;
        int rg = rb * 64 + mi * 16 + lg * 4 + r;
        int tt = rg >> 9, b = rg & 511;
        float v = acc[mi][ni][r] + fc_b[ng];
        float mask = (tt < length[b]) ? 1.0f : 0.0f;
        if      (ng < 64)    out[(size_t)rg * 64 + ng] = sigm(v) * mask;
        else if (ng < 1088)  out[(size_t)1572864 + (size_t)rg * 1024 + (ng - 64)] = fmaxf(v, 0.f) * mask;
        else if (ng == 1088) out[(size_t)26738688 + rg] = sigm(v) * mask;
        else                 out[(size_t)26763264 + rg] = __expf(v) * mask;
      }
}

extern "C" void kernel_launch(void* const* d_in, const int* in_sizes, int n_in,
                              void* d_out, int out_size, void* d_ws, size_t ws_size,
                              hipStream_t stream){
  const float* image  = (const float*)d_in[0];
  const float* vp     = (const float*)d_in[1];
  const float* label  = (const float*)d_in[2];
  const int*   length = (const int*)  d_in[3];
  const float* fc_h_w = (const float*)d_in[4];
  const float* fc_h_b = (const float*)d_in[5];
  const float* fc_m_w = (const float*)d_in[6];
  const float* fc_m_b = (const float*)d_in[7];
  const float* w_ih   = (const float*)d_in[8];
  const float* w_hh   = (const float*)d_in[9];
  const float* b_ih   = (const float*)d_in[10];
  const float* b_hh   = (const float*)d_in[11];
  const float* fc_w   = (const float*)d_in[12];
  const float* fc_b   = (const float*)d_in[13];
  float* out = (float*)d_out;

  char* ws = (char*)d_ws;
  bf16_t* imb    = (bf16_t*)(ws + 0);           // 1 MB
  bf16_t* hs     = (bf16_t*)(ws + 1048576);     // 49 x 512 x 1088 bf16 = 54.6 MB
  float*  m      = (float*) (ws + 55640064);    // 2 MB
  float*  xconst = (float*) (ws + 57737216);    // 8 MB
  bf16_t* whhx   = (bf16_t*)(ws + 66125824);    // 8.9 MB
  bf16_t* wimgb  = (bf16_t*)(ws + 75038720);    // 8 MB
  bf16_t* fchwb  = (bf16_t*)(ws + 83427328);    // 2 MB
  bf16_t* fcmwb  = (bf16_t*)(ws + 85524480);    // 2 MB
  bf16_t* fcwb   = (bf16_t*)(ws + 87621632);    // 2.2 MB (ends 89853952)

  k_mean   <<<dim3(512),  dim3(256), 0, stream>>>(image, imb);
  k_convert<<<dim3(2048), dim3(256), 0, stream>>>(w_hh, fc_h_w, fc_m_w, fc_w, label, w_ih,
                                                  whhx, fchwb, fcmwb, fcwb, wimgb, hs);
  k_vpc    <<<dim3(8192), dim3(256), 0, stream>>>(w_ih, vp, b_ih, b_hh, xconst);
  k_init_gemm<<<dim3(48, 8), dim3(256), 0, stream>>>(imb, fchwb, fcmwb, wimgb,
                                                     fc_h_b, fc_m_b, hs, m, xconst);
  for (int t = 0; t < Tn; ++t){
    k_step<<<dim3(32, 8), dim3(256), 0, stream>>>(hs + (size_t)t * HSTEP,
                                                  hs + (size_t)(t + 1) * HSTEP,
                                                  whhx, xconst, w_ih, m, t);
  }
  k_out<<<dim3(3456), dim3(256), 0, stream>>>(hs + (size_t)HSTEP, fcwb, fc_b, length, out);
}

// Round 14
// 979.858 us; speedup vs baseline: 3.7341x; 1.1449x over previous
//
#include <hip/hip_runtime.h>
#include <hip/hip_bf16.h>
#include <cstdint>

// ReportDecoder: B=512,S=49,E=1024,H=1024,V2=16,L=64,T=48, D_IN=1105
// Round 14: r13 + ONE change — k_step LDS bank-conflict fix (T2, rule #21):
// linear [row][64] LDS rows are 128B => 16-way conflict on ds_read_b128 (m201).
// Fix: pre-swizzle the per-lane GLOBAL source (unit u^rsub) so linear
// global_load_lds lands data swizzled; read back with unit (kk*4+hi)^(lr&7).
// Involution verified; banks spread over all 8 quads. Everything else = r13.

typedef __bf16 bf16_t;
typedef bf16_t bf16x8 __attribute__((ext_vector_type(8)));
typedef bf16_t bf16x4 __attribute__((ext_vector_type(4)));
typedef float  f32x4  __attribute__((ext_vector_type(4)));

#define Bn    512
#define Sn    49
#define En    1024
#define Hn    1024
#define Ln    64
#define Tn    48
#define DINn  1105
#define NOn   1090
#define HLD   1088          // h row stride (1024 h + 64 label)
#define HSTEP 557056        // 512*1088 elements per step slab

#define BM   64
#define LDSP 72             // padded K-stride for init/out GEMM LDS tiles

__device__ __forceinline__ float sigm(float x){ return 1.0f / (1.0f + __expf(-x)); }

// ---------- image mean ----------
__global__ __launch_bounds__(256) void k_mean(const float* __restrict__ image,
                                              bf16_t* __restrict__ imb){
  int b  = blockIdx.x;
  int e0 = threadIdx.x * 4;
  const float* p = image + (size_t)b * (Sn * En) + e0;
  float4 acc = make_float4(0.f, 0.f, 0.f, 0.f);
  for (int s = 0; s < Sn; ++s){
    float4 v = *reinterpret_cast<const float4*>(p + (size_t)s * En);
    acc.x += v.x; acc.y += v.y; acc.z += v.z; acc.w += v.w;
  }
  const float inv = 1.0f / 49.0f;
  bf16x4 o;
  o[0] = (bf16_t)(acc.x * inv); o[1] = (bf16_t)(acc.y * inv);
  o[2] = (bf16_t)(acc.z * inv); o[3] = (bf16_t)(acc.w * inv);
  *reinterpret_cast<bf16x4*>(imb + (size_t)b * En + e0) = o;
}

// ---------- conversions: whhx concat, fc weights, wimg, label scatter into hs ----------
__global__ __launch_bounds__(256) void k_convert(
    const float* __restrict__ w_hh,  const float* __restrict__ fc_h_w,
    const float* __restrict__ fc_m_w,const float* __restrict__ fc_w,
    const float* __restrict__ label, const float* __restrict__ w_ih,
    bf16_t* __restrict__ whhx,  bf16_t* __restrict__ fchwb,
    bf16_t* __restrict__ fcmwb, bf16_t* __restrict__ fcwb,
    bf16_t* __restrict__ wimgb, bf16_t* __restrict__ hs){
  const int E0 = 4096 * 1088;
  const int E1 = E0 + 1024 * 1024;
  const int E2 = E1 + 1024 * 1024;
  const int E3 = E2 + 1090 * 1024;
  const int E4 = E3 + 4096 * 1024;
  const int E5 = E4 + 48 * 512 * 64;
  int stride = gridDim.x * blockDim.x;
  for (int i = blockIdx.x * blockDim.x + threadIdx.x; i < E5; i += stride){
    if (i < E0){
      int n = i / 1088, k = i - n * 1088;
      float v = (k < 1024) ? w_hh[(size_t)n * 1024 + k]
                           : w_ih[(size_t)n * DINn + 1041 + (k - 1024)];
      whhx[i] = (bf16_t)v;
    } else if (i < E1){ int j = i - E0; fchwb[j] = (bf16_t)fc_h_w[j]; }
    else if (i < E2){ int j = i - E1; fcmwb[j] = (bf16_t)fc_m_w[j]; }
    else if (i < E3){ int j = i - E2; fcwb[j]  = (bf16_t)fc_w[j]; }
    else if (i < E4){
      int j = i - E3; int n = j >> 10, k = j & 1023;
      wimgb[j] = (bf16_t)w_ih[(size_t)n * DINn + k];
    } else {
      int j = i - E4;
      int t = j >> 15, rem = j & 32767, row = rem >> 6, c = rem & 63;
      float v = (t == 0) ? 0.f : label[(size_t)row * (Sn * Ln) + (t - 1) * 64 + c];
      hs[((size_t)t * 512 + row) * HLD + 1024 + c] = (bf16_t)v;
    }
  }
}

// ---------- xconst pre-pass ----------
__global__ __launch_bounds__(256) void k_vpc(const float* __restrict__ w_ih,
                                             const float* __restrict__ vp,
                                             const float* __restrict__ b_ih,
                                             const float* __restrict__ b_hh,
                                             float* __restrict__ xconst){
  int idx = blockIdx.x * 256 + threadIdx.x;
  int b = idx >> 12, n = idx & 4095;
  float acc = b_ih[n] + b_hh[n];
  const float* w = w_ih + (size_t)n * DINn + En;
  const float* v = vp + b * 16;
  #pragma unroll
  for (int j = 0; j < 16; ++j) acc += v[j] * w[j];
  xconst[idx] = acc;
}

// ---------- padded-LDS helpers (init/out GEMMs) ----------
__device__ __forceinline__ void stageA(bf16_t* sA, const bf16_t* gptr, int ld, int tid){
  #pragma unroll
  for (int i = 0; i < 2; ++i){
    int idx = tid + i * 256;
    int r = idx >> 3, v = idx & 7;
    *reinterpret_cast<bf16x8*>(sA + r * LDSP + v * 8) =
      *reinterpret_cast<const bf16x8*>(gptr + (size_t)r * ld + v * 8);
  }
}

__device__ __forceinline__ void mma_tile(const bf16_t* sA, const bf16_t* sB,
                                         f32x4 (&acc)[4][2], int lane, int w){
  int lr = lane & 15;
  int lk = (lane >> 4) * 8;
  #pragma unroll
  for (int kk = 0; kk < 2; ++kk){
    bf16x8 a[4], bb[2];
    #pragma unroll
    for (int mi = 0; mi < 4; ++mi)
      a[mi] = *reinterpret_cast<const bf16x8*>(sA + (mi * 16 + lr) * LDSP + kk * 32 + lk);
    #pragma unroll
    for (int ni = 0; ni < 2; ++ni)
      bb[ni] = *reinterpret_cast<const bf16x8*>(sB + (w * 32 + ni * 16 + lr) * LDSP + kk * 32 + lk);
    #pragma unroll
    for (int mi = 0; mi < 4; ++mi)
      #pragma unroll
      for (int ni = 0; ni < 2; ++ni)
        acc[mi][ni] = __builtin_amdgcn_mfma_f32_16x16x32_bf16(a[mi], bb[ni], acc[mi][ni], 0, 0, 0);
  }
}

// swizzled-LDS variant for k_step (linear chunks, unit ^= (row&7))
__device__ __forceinline__ void mma_tile_swz(const bf16_t* sA, const bf16_t* sB,
                                             f32x4 (&acc)[4][2], int lane, int w){
  int lr  = lane & 15;
  int key = lr & 7;
  int ub  = lane >> 4;                 // 0..3
  #pragma unroll
  for (int kk = 0; kk < 2; ++kk){
    int uo = ((kk * 4 + ub) ^ key) * 8;
    bf16x8 a[4], bb[2];
    #pragma unroll
    for (int mi = 0; mi < 4; ++mi)
      a[mi] = *reinterpret_cast<const bf16x8*>(sA + (mi * 16 + lr) * 64 + uo);
    #pragma unroll
    for (int ni = 0; ni < 2; ++ni)
      bb[ni] = *reinterpret_cast<const bf16x8*>(sB + (w * 32 + ni * 16 + lr) * 64 + uo);
    #pragma unroll
    for (int mi = 0; mi < 4; ++mi)
      #pragma unroll
      for (int ni = 0; ni < 2; ++ni)
        acc[mi][ni] = __builtin_amdgcn_mfma_f32_16x16x32_bf16(a[mi], bb[ni], acc[mi][ni], 0, 0, 0);
  }
}

// ---------- init GEMM: h0 (stride 1088), m0, xconst += im@Wimg^T ----------
__global__ __launch_bounds__(256) void k_init_gemm(
    const bf16_t* __restrict__ imb,  const bf16_t* __restrict__ fchw,
    const bf16_t* __restrict__ fcmw, const bf16_t* __restrict__ wimg,
    const float* __restrict__ fc_h_b,const float* __restrict__ fc_m_b,
    bf16_t* __restrict__ h0, float* __restrict__ m0, float* __restrict__ xconst){
  __shared__ __align__(16) unsigned char smem[(BM + 128) * LDSP * 2];
  bf16_t* sA = (bf16_t*)smem;
  bf16_t* sB = (bf16_t*)(smem + BM * LDSP * 2);
  int tid = threadIdx.x;
  int cb = blockIdx.x, rb = blockIdx.y;
  int nBase = cb * 128;
  const bf16_t* Bsrc; int nOff;
  if      (nBase < 1024){ Bsrc = fchw; nOff = nBase; }
  else if (nBase < 2048){ Bsrc = fcmw; nOff = nBase - 1024; }
  else                  { Bsrc = wimg; nOff = nBase - 2048; }

  f32x4 acc[4][2] = {};
  int lane = tid & 63, w = tid >> 6;
  for (int kt = 0; kt < 16; ++kt){
    stageA(sA, imb + (size_t)(rb * 64) * 1024 + kt * 64, 1024, tid);
    #pragma unroll
    for (int i = 0; i < 4; ++i){
      int idx = tid + i * 256;
      int r = idx >> 3, v = idx & 7;
      *reinterpret_cast<bf16x8*>(sB + r * LDSP + v * 8) =
        *reinterpret_cast<const bf16x8*>(Bsrc + (size_t)(nOff + r) * 1024 + kt * 64 + v * 8);
    }
    __syncthreads();
    mma_tile(sA, sB, acc, lane, w);
    __syncthreads();
  }
  int lr = lane & 15, lg = lane >> 4;
  #pragma unroll
  for (int mi = 0; mi < 4; ++mi)
    #pragma unroll
    for (int ni = 0; ni < 2; ++ni)
      #pragma unroll
      for (int r = 0; r < 4; ++r){
        int ng   = nBase + w * 32 + ni * 16 + lr;
        int rowg = rb * 64 + mi * 16 + lg * 4 + r;
        float v = acc[mi][ni][r];
        if (ng < 1024){
          h0[(size_t)rowg * HLD + ng] = (bf16_t)tanhf(v + fc_h_b[ng]);
        } else if (ng < 2048){
          int n = ng - 1024;
          m0[(size_t)rowg * 1024 + n] = tanhf(v + fc_m_b[n]);
        } else {
          int n = ng - 2048;
          xconst[(size_t)rowg * 4096 + n] += v;
        }
      }
}

// ---------- per-step fused gates GEMM + LSTM cell (5-buffer depth-4 pipeline,
//            bank-conflict-free via source-swizzled global_load_lds) ----------
__global__ __launch_bounds__(256) void k_step(
    const bf16_t* __restrict__ hin,
    bf16_t* __restrict__ hout,
    const bf16_t* __restrict__ whhx,   // 4096 x 1088
    const float* __restrict__ xconst,  // 512 x 4096
    const float* __restrict__ w_ih,    // begin col 1040
    float* __restrict__ m,             // 512 x 1024 f32
    int t){
  __shared__ __align__(16) unsigned char smem[122880];  // 5 x 24576
  float* gbuf = (float*)smem;                           // reused post-loop
  int tid = threadIdx.x;
  int cb = blockIdx.x, rb = blockIdx.y;
  int lane = tid & 63, w = tid >> 6;
  int rsub = lane >> 3;
  int usw  = (((lane & 7) ^ rsub) & 7) * 8;  // swizzled unit offset (elements)
  f32x4 acc[4][2] = {};

  auto stage = [&](int buf, int kt){
    int kb = kt * 64;
    char* base = (char*)smem + buf * 24576;
    #pragma unroll
    for (int c = 0; c < 2; ++c){
      int q = w * 2 + c;
      int r = q * 8 + rsub;
      const bf16_t* g = hin + (size_t)(rb * 64 + r) * HLD + kb + usw;
      __builtin_amdgcn_global_load_lds((const void*)g, (void*)(base + q * 1024), 16, 0, 0);
    }
    #pragma unroll
    for (int c = 0; c < 4; ++c){
      int q = w * 4 + c;
      int r = q * 8 + rsub;
      int n = (r >> 5) * 1024 + cb * 32 + (r & 31);
      const bf16_t* g = whhx + (size_t)n * HLD + kb + usw;
      __builtin_amdgcn_global_load_lds((const void*)g, (void*)(base + 8192 + q * 1024), 16, 0, 0);
    }
  };

  stage(0, 0);
  stage(1, 1);
  stage(2, 2);
  stage(3, 3);
  for (int kt = 0; kt < 13; ++kt){
    stage((kt + 4) % 5, kt + 4);
    asm volatile("s_waitcnt vmcnt(24)" ::: "memory");   // my 6 loads for buf[kt] done
    __builtin_amdgcn_sched_barrier(0);
    __builtin_amdgcn_s_barrier();                        // everyone's buf[kt] done
    bf16_t* cA = (bf16_t*)((char*)smem + (kt % 5) * 24576);
    mma_tile_swz(cA, cA + 4096, acc, lane, w);
    __builtin_amdgcn_s_barrier();                        // WAR guard before re-stage
  }
  asm volatile("s_waitcnt vmcnt(18)" ::: "memory");
  __builtin_amdgcn_sched_barrier(0);
  __builtin_amdgcn_s_barrier();
  { bf16_t* cA = (bf16_t*)((char*)smem + (13 % 5) * 24576);
    mma_tile_swz(cA, cA + 4096, acc, lane, w); }
  __builtin_amdgcn_s_barrier();
  asm volatile("s_waitcnt vmcnt(12)" ::: "memory");
  __builtin_amdgcn_sched_barrier(0);
  __builtin_amdgcn_s_barrier();
  { bf16_t* cA = (bf16_t*)((char*)smem + (14 % 5) * 24576);
    mma_tile_swz(cA, cA + 4096, acc, lane, w); }
  __builtin_amdgcn_s_barrier();
  asm volatile("s_waitcnt vmcnt(6)" ::: "memory");
  __builtin_amdgcn_sched_barrier(0);
  __builtin_amdgcn_s_barrier();
  { bf16_t* cA = (bf16_t*)((char*)smem + (15 % 5) * 24576);
    mma_tile_swz(cA, cA + 4096, acc, lane, w); }
  __builtin_amdgcn_s_barrier();
  asm volatile("s_waitcnt vmcnt(0)" ::: "memory");
  __builtin_amdgcn_sched_barrier(0);
  __builtin_amdgcn_s_barrier();
  { bf16_t* cA = (bf16_t*)((char*)smem + (16 % 5) * 24576);
    mma_tile_swz(cA, cA + 4096, acc, lane, w); }
  __syncthreads();   // full drain before LDS reuse as gbuf

  // epilogue: xconst (+ begin at t==0), gate exchange via LDS, fused cell
  int lr = lane & 15, lg = lane >> 4;
  #pragma unroll
  for (int mi = 0; mi < 4; ++mi)
    #pragma unroll
    for (int ni = 0; ni < 2; ++ni)
      #pragma unroll
      for (int r = 0; r < 4; ++r){
        int cl = ni * 16 + lr;
        int ng = w * 1024 + cb * 32 + cl;
        int rl = mi * 16 + lg * 4 + r;
        int rowg = rb * 64 + rl;
        float v = acc[mi][ni][r] + xconst[(size_t)rowg * 4096 + ng];
        if (t == 0) v += w_ih[(size_t)ng * DINn + 1040];
        gbuf[(w * 64 + rl) * 33 + cl] = v;
      }
  __syncthreads();
  #pragma unroll
  for (int rep = 0; rep < 8; ++rep){
    int cell = tid + rep * 256;
    int rl = cell >> 5, cl = cell & 31;
    float gi = gbuf[(0 * 64 + rl) * 33 + cl];
    float gf = gbuf[(1 * 64 + rl) * 33 + cl];
    float gg = gbuf[(2 * 64 + rl) * 33 + cl];
    float go = gbuf[(3 * 64 + rl) * 33 + cl];
    int rowg = rb * 64 + rl, colg = cb * 32 + cl;
    size_t o = (size_t)rowg * 1024 + colg;
    float mo = m[o];
    float mn = sigm(gf) * mo + sigm(gi) * tanhf(gg);
    m[o] = mn;
    float hn = sigm(go) * tanhf(mn);
    hout[(size_t)rowg * HLD + colg] = (bf16_t)hn;
  }
}

// ---------- batched out GEMM (N=128) + XCD A-locality swizzle ----------
__global__ __launch_bounds__(256) void k_out(
    const bf16_t* __restrict__ h,      // hs + HSTEP: 24576 rows, stride 1088
    const bf16_t* __restrict__ fcwb,
    const float* __restrict__ fc_b, const int* __restrict__ length,
    float* __restrict__ out){
  __shared__ __align__(16) unsigned char smem[(BM + 128) * LDSP * 2];
  bf16_t* sA = (bf16_t*)smem;
  bf16_t* sB = (bf16_t*)(smem + BM * LDSP * 2);
  int tid = threadIdx.x;
  int id  = blockIdx.x;
  int xcd = id & 7;
  int rem = id >> 3;
  int cb  = rem % 9;
  int grp = rem / 9;
  int rb  = xcd + 8 * grp;               // 0..383
  f32x4 acc[4][2] = {};
  int lane = tid & 63, w = tid >> 6;
  for (int kt = 0; kt < 16; ++kt){
    stageA(sA, h + (size_t)(rb * 64) * HLD + kt * 64, HLD, tid);
    #pragma unroll
    for (int i = 0; i < 4; ++i){
      int idx = tid + i * 256;
      int r = idx >> 3, v = idx & 7;
      int n = cb * 128 + r;
      bf16x8 val = {};
      if (n < NOn)
        val = *reinterpret_cast<const bf16x8*>(fcwb + (size_t)n * 1024 + kt * 64 + v * 8);
      *reinterpret_cast<bf16x8*>(sB + r * LDSP + v * 8) = val;
    }
    __syncthreads();
    mma_tile(sA, sB, acc, lane, w);
    __syncthreads();
  }
  int lr = lane & 15, lg = lane >> 4;
  #pragma unroll
  for (int mi = 0; mi < 4; ++mi)
    #pragma unroll
    for (int ni = 0; ni < 2; ++ni)
      #pragma unroll
      for (int r = 0; r < 4; ++r){
        int ng = cb * 128 + w * 32 + ni * 16 + lr;
        if (ng >= NOn) continue;
        int rg = rb * 64 + mi * 16 + lg * 4 + r;
        int tt = rg >> 9, b = rg & 511;
        float v = acc[mi][ni][r] + fc_b[ng];
        float mask = (tt < length[b]) ? 1.0f : 0.0f;
        if      (ng < 64)    out[(size_t)rg * 64 + ng] = sigm(v) * mask;
        else if (ng < 1088)  out[(size_t)1572864 + (size_t)rg * 1024 + (ng - 64)] = fmaxf(v, 0.f) * mask;
        else if (ng == 1088) out[(size_t)26738688 + rg] = sigm(v) * mask;
        else                 out[(size_t)26763264 + rg] = __expf(v) * mask;
      }
}

extern "C" void kernel_launch(void* const* d_in, const int* in_sizes, int n_in,
                              void* d_out, int out_size, void* d_ws, size_t ws_size,
                              hipStream_t stream){
  const float* image  = (const float*)d_in[0];
  const float* vp     = (const float*)d_in[1];
  const float* label  = (const float*)d_in[2];
  const int*   length = (const int*)  d_in[3];
  const float* fc_h_w = (const float*)d_in[4];
  const float* fc_h_b = (const float*)d_in[5];
  const float* fc_m_w = (const float*)d_in[6];
  const float* fc_m_b = (const float*)d_in[7];
  const float* w_ih   = (const float*)d_in[8];
  const float* w_hh   = (const float*)d_in[9];
  const float* b_ih   = (const float*)d_in[10];
  const float* b_hh   = (const float*)d_in[11];
  const float* fc_w   = (const float*)d_in[12];
  const float* fc_b   = (const float*)d_in[13];
  float* out = (float*)d_out;

  char* ws = (char*)d_ws;
  bf16_t* imb    = (bf16_t*)(ws + 0);           // 1 MB
  bf16_t* hs     = (bf16_t*)(ws + 1048576);     // 49 x 512 x 1088 bf16 = 54.6 MB
  float*  m      = (float*) (ws + 55640064);    // 2 MB
  float*  xconst = (float*) (ws + 57737216);    // 8 MB
  bf16_t* whhx   = (bf16_t*)(ws + 66125824);    // 8.9 MB
  bf16_t* wimgb  = (bf16_t*)(ws + 75038720);    // 8 MB
  bf16_t* fchwb  = (bf16_t*)(ws + 83427328);    // 2 MB
  bf16_t* fcmwb  = (bf16_t*)(ws + 85524480);    // 2 MB
  bf16_t* fcwb   = (bf16_t*)(ws + 87621632);    // 2.2 MB (ends 89853952)

  k_mean   <<<dim3(512),  dim3(256), 0, stream>>>(image, imb);
  k_convert<<<dim3(2048), dim3(256), 0, stream>>>(w_hh, fc_h_w, fc_m_w, fc_w, label, w_ih,
                                                  whhx, fchwb, fcmwb, fcwb, wimgb, hs);
  k_vpc    <<<dim3(8192), dim3(256), 0, stream>>>(w_ih, vp, b_ih, b_hh, xconst);
  k_init_gemm<<<dim3(48, 8), dim3(256), 0, stream>>>(imb, fchwb, fcmwb, wimgb,
                                                     fc_h_b, fc_m_b, hs, m, xconst);
  for (int t = 0; t < Tn; ++t){
    k_step<<<dim3(32, 8), dim3(256), 0, stream>>>(hs + (size_t)t * HSTEP,
                                                  hs + (size_t)(t + 1) * HSTEP,
                                                  whhx, xconst, w_ih, m, t);
  }
  k_out<<<dim3(3456), dim3(256), 0, stream>>>(hs + (size_t)HSTEP, fcwb, fc_b, length, out);
}

// Round 15
// 912.361 us; speedup vs baseline: 4.0104x; 1.0740x over previous
//
#include <hip/hip_runtime.h>
#include <hip/hip_bf16.h>
#include <cstdint>

// ReportDecoder: B=512,S=49,E=1024,H=1024,V2=16,L=64,T=48, D_IN=1105
// Round 15: k_step B-direct — weights bypass LDS entirely:
//  - k_convert packs W_hh|W_lab into fragment-order tiles whht[cb][17][16][512]
//    (per-lane 16B units, coalesced 1KB/wave loads).
//  - k_step: A = 5-buffer swizzled global_load_lds pipeline (8KB bufs, as r14);
//    B = global->register, triple-buffered 2 iters ahead (full unroll, static idx).
//    Uniform asm vmcnt(8) guards A-landing (set-analysis safe under reordering);
//    compiler guards B register deps. LDS/iter 73KB -> 40KB.
// k_out / preamble unchanged from r14.

typedef __bf16 bf16_t;
typedef bf16_t bf16x8 __attribute__((ext_vector_type(8)));
typedef bf16_t bf16x4 __attribute__((ext_vector_type(4)));
typedef float  f32x4  __attribute__((ext_vector_type(4)));

#define Bn    512
#define Sn    49
#define En    1024
#define Hn    1024
#define Ln    64
#define Tn    48
#define DINn  1105
#define NOn   1090
#define HLD   1088          // h row stride (1024 h + 64 label)
#define HSTEP 557056        // 512*1088 elements per step slab

#define BM   64
#define LDSP 72             // padded K-stride for init/out GEMM LDS tiles

__device__ __forceinline__ float sigm(float x){ return 1.0f / (1.0f + __expf(-x)); }

// ---------- image mean ----------
__global__ __launch_bounds__(256) void k_mean(const float* __restrict__ image,
                                              bf16_t* __restrict__ imb){
  int b  = blockIdx.x;
  int e0 = threadIdx.x * 4;
  const float* p = image + (size_t)b * (Sn * En) + e0;
  float4 acc = make_float4(0.f, 0.f, 0.f, 0.f);
  for (int s = 0; s < Sn; ++s){
    float4 v = *reinterpret_cast<const float4*>(p + (size_t)s * En);
    acc.x += v.x; acc.y += v.y; acc.z += v.z; acc.w += v.w;
  }
  const float inv = 1.0f / 49.0f;
  bf16x4 o;
  o[0] = (bf16_t)(acc.x * inv); o[1] = (bf16_t)(acc.y * inv);
  o[2] = (bf16_t)(acc.z * inv); o[3] = (bf16_t)(acc.w * inv);
  *reinterpret_cast<bf16x4*>(imb + (size_t)b * En + e0) = o;
}

// ---------- conversions: whht packed tiles, fc weights, wimg, label scatter ----------
__global__ __launch_bounds__(256) void k_convert(
    const float* __restrict__ w_hh,  const float* __restrict__ fc_h_w,
    const float* __restrict__ fc_m_w,const float* __restrict__ fc_w,
    const float* __restrict__ label, const float* __restrict__ w_ih,
    bf16_t* __restrict__ whht,  bf16_t* __restrict__ fchwb,
    bf16_t* __restrict__ fcmwb, bf16_t* __restrict__ fcwb,
    bf16_t* __restrict__ wimgb, bf16_t* __restrict__ hs){
  const int E0 = 32 * 17 * 16 * 512;     // whht packed (= 4096*1088)
  const int E1 = E0 + 1024 * 1024;
  const int E2 = E1 + 1024 * 1024;
  const int E3 = E2 + 1090 * 1024;
  const int E4 = E3 + 4096 * 1024;
  const int E5 = E4 + 48 * 512 * 64;
  int stride = gridDim.x * blockDim.x;
  for (int i = blockIdx.x * blockDim.x + threadIdx.x; i < E5; i += stride){
    if (i < E0){
      // whht[((cb*17+kt)*16 + (w*4+ni*2+kk))*512 + lane*8 + e]
      int e = i & 7, l = (i >> 3) & 63, g = (i >> 9) & 15;
      int rest = i >> 13;                // cb*17 + kt
      int kt = rest % 17, cbb = rest / 17;
      int wv = g >> 2, ni = (g >> 1) & 1, kk = g & 1;
      int n = wv * 1024 + cbb * 32 + ni * 16 + (l & 15);
      int k = kt * 64 + kk * 32 + (l >> 4) * 8 + e;
      float v = (k < 1024) ? w_hh[(size_t)n * 1024 + k]
                           : w_ih[(size_t)n * DINn + 1041 + (k - 1024)];
      whht[i] = (bf16_t)v;
    } else if (i < E1){ int j = i - E0; fchwb[j] = (bf16_t)fc_h_w[j]; }
    else if (i < E2){ int j = i - E1; fcmwb[j] = (bf16_t)fc_m_w[j]; }
    else if (i < E3){ int j = i - E2; fcwb[j]  = (bf16_t)fc_w[j]; }
    else if (i < E4){
      int j = i - E3; int n = j >> 10, k = j & 1023;
      wimgb[j] = (bf16_t)w_ih[(size_t)n * DINn + k];
    } else {
      int j = i - E4;
      int t = j >> 15, rem = j & 32767, row = rem >> 6, c = rem & 63;
      float v = (t == 0) ? 0.f : label[(size_t)row * (Sn * Ln) + (t - 1) * 64 + c];
      hs[((size_t)t * 512 + row) * HLD + 1024 + c] = (bf16_t)v;
    }
  }
}

// ---------- xconst pre-pass ----------
__global__ __launch_bounds__(256) void k_vpc(const float* __restrict__ w_ih,
                                             const float* __restrict__ vp,
                                             const float* __restrict__ b_ih,
                                             const float* __restrict__ b_hh,
                                             float* __restrict__ xconst){
  int idx = blockIdx.x * 256 + threadIdx.x;
  int b = idx >> 12, n = idx & 4095;
  float acc = b_ih[n] + b_hh[n];
  const float* w = w_ih + (size_t)n * DINn + En;
  const float* v = vp + b * 16;
  #pragma unroll
  for (int j = 0; j < 16; ++j) acc += v[j] * w[j];
  xconst[idx] = acc;
}

// ---------- padded-LDS helpers (init/out GEMMs) ----------
__device__ __forceinline__ void stageAp(bf16_t* sA, const bf16_t* gptr, int ld, int tid){
  #pragma unroll
  for (int i = 0; i < 2; ++i){
    int idx = tid + i * 256;
    int r = idx >> 3, v = idx & 7;
    *reinterpret_cast<bf16x8*>(sA + r * LDSP + v * 8) =
      *reinterpret_cast<const bf16x8*>(gptr + (size_t)r * ld + v * 8);
  }
}

__device__ __forceinline__ void mma_tile(const bf16_t* sA, const bf16_t* sB,
                                         f32x4 (&acc)[4][2], int lane, int w){
  int lr = lane & 15;
  int lk = (lane >> 4) * 8;
  #pragma unroll
  for (int kk = 0; kk < 2; ++kk){
    bf16x8 a[4], bb[2];
    #pragma unroll
    for (int mi = 0; mi < 4; ++mi)
      a[mi] = *reinterpret_cast<const bf16x8*>(sA + (mi * 16 + lr) * LDSP + kk * 32 + lk);
    #pragma unroll
    for (int ni = 0; ni < 2; ++ni)
      bb[ni] = *reinterpret_cast<const bf16x8*>(sB + (w * 32 + ni * 16 + lr) * LDSP + kk * 32 + lk);
    #pragma unroll
    for (int mi = 0; mi < 4; ++mi)
      #pragma unroll
      for (int ni = 0; ni < 2; ++ni)
        acc[mi][ni] = __builtin_amdgcn_mfma_f32_16x16x32_bf16(a[mi], bb[ni], acc[mi][ni], 0, 0, 0);
  }
}

// ---------- init GEMM: h0 (stride 1088), m0, xconst += im@Wimg^T ----------
__global__ __launch_bounds__(256) void k_init_gemm(
    const bf16_t* __restrict__ imb,  const bf16_t* __restrict__ fchw,
    const bf16_t* __restrict__ fcmw, const bf16_t* __restrict__ wimg,
    const float* __restrict__ fc_h_b,const float* __restrict__ fc_m_b,
    bf16_t* __restrict__ h0, float* __restrict__ m0, float* __restrict__ xconst){
  __shared__ __align__(16) unsigned char smem[(BM + 128) * LDSP * 2];
  bf16_t* sA = (bf16_t*)smem;
  bf16_t* sB = (bf16_t*)(smem + BM * LDSP * 2);
  int tid = threadIdx.x;
  int cb = blockIdx.x, rb = blockIdx.y;
  int nBase = cb * 128;
  const bf16_t* Bsrc; int nOff;
  if      (nBase < 1024){ Bsrc = fchw; nOff = nBase; }
  else if (nBase < 2048){ Bsrc = fcmw; nOff = nBase - 1024; }
  else                  { Bsrc = wimg; nOff = nBase - 2048; }

  f32x4 acc[4][2] = {};
  int lane = tid & 63, w = tid >> 6;
  for (int kt = 0; kt < 16; ++kt){
    stageAp(sA, imb + (size_t)(rb * 64) * 1024 + kt * 64, 1024, tid);
    #pragma unroll
    for (int i = 0; i < 4; ++i){
      int idx = tid + i * 256;
      int r = idx >> 3, v = idx & 7;
      *reinterpret_cast<bf16x8*>(sB + r * LDSP + v * 8) =
        *reinterpret_cast<const bf16x8*>(Bsrc + (size_t)(nOff + r) * 1024 + kt * 64 + v * 8);
    }
    __syncthreads();
    mma_tile(sA, sB, acc, lane, w);
    __syncthreads();
  }
  int lr = lane & 15, lg = lane >> 4;
  #pragma unroll
  for (int mi = 0; mi < 4; ++mi)
    #pragma unroll
    for (int ni = 0; ni < 2; ++ni)
      #pragma unroll
      for (int r = 0; r < 4; ++r){
        int ng   = nBase + w * 32 + ni * 16 + lr;
        int rowg = rb * 64 + mi * 16 + lg * 4 + r;
        float v = acc[mi][ni][r];
        if (ng < 1024){
          h0[(size_t)rowg * HLD + ng] = (bf16_t)tanhf(v + fc_h_b[ng]);
        } else if (ng < 2048){
          int n = ng - 1024;
          m0[(size_t)rowg * 1024 + n] = tanhf(v + fc_m_b[n]);
        } else {
          int n = ng - 2048;
          xconst[(size_t)rowg * 4096 + n] += v;
        }
      }
}

// ---------- per-step fused gates GEMM + LSTM cell ----------
// grid (32,8). A: 5-buffer swizzled global_load_lds pipeline (8KB bufs).
// B: packed whht tiles -> registers, triple-buffered 2 iters ahead. vmcnt(8).
__global__ __launch_bounds__(256) void k_step(
    const bf16_t* __restrict__ hin,
    bf16_t* __restrict__ hout,
    const bf16_t* __restrict__ whht,   // packed [cb][17][16][512]
    const float* __restrict__ xconst,  // 512 x 4096
    const float* __restrict__ w_ih,    // begin col 1040
    float* __restrict__ m,             // 512 x 1024 f32
    int t){
  __shared__ __align__(16) unsigned char smem[40960];   // 5 x 8192 (A only)
  float* gbuf = (float*)smem;                           // reused post-loop
  int tid = threadIdx.x;
  int cb = blockIdx.x, rb = blockIdx.y;
  int lane = tid & 63, w = tid >> 6;
  int rsub = lane >> 3;
  int usw  = (((lane & 7) ^ rsub) & 7) * 8;  // swizzled unit offset (elements)
  int lr = lane & 15;
  int key = lr & 7;
  int ub = lane >> 4;
  f32x4 acc[4][2] = {};

  const bf16_t* bbase = whht + (((size_t)cb * 17) << 13) + ((w * 4) << 9) + lane * 8;

  bf16x8 breg[3][2][2];

  auto stageA = [&](int buf, int kt){
    char* base = (char*)smem + buf * 8192;
    #pragma unroll
    for (int c = 0; c < 2; ++c){
      int q = w * 2 + c;
      int r = q * 8 + rsub;
      const bf16_t* g = hin + (size_t)(rb * 64 + r) * HLD + kt * 64 + usw;
      __builtin_amdgcn_global_load_lds((const void*)g, (void*)(base + q * 1024), 16, 0, 0);
    }
  };

  // prologue: B(0), B(1) then A stages 0..3
  #pragma unroll
  for (int ni = 0; ni < 2; ++ni)
    #pragma unroll
    for (int kk = 0; kk < 2; ++kk){
      breg[0][ni][kk] = *reinterpret_cast<const bf16x8*>(bbase + ((ni * 2 + kk) << 9));
      breg[1][ni][kk] = *reinterpret_cast<const bf16x8*>(bbase + ((size_t)1 << 13) + ((ni * 2 + kk) << 9));
    }
  stageA(0, 0); stageA(1, 1); stageA(2, 2); stageA(3, 3);

  #pragma unroll
  for (int kt = 0; kt < 17; ++kt){
    if (kt + 2 <= 16){
      const int s2 = (kt + 2) % 3;
      #pragma unroll
      for (int ni = 0; ni < 2; ++ni)
        #pragma unroll
        for (int kk = 0; kk < 2; ++kk)
          breg[s2][ni][kk] = *reinterpret_cast<const bf16x8*>(
              bbase + ((size_t)(kt + 2) << 13) + ((ni * 2 + kk) << 9));
    }
    if (kt + 4 <= 16) stageA((kt + 4) % 5, kt + 4);
    asm volatile("s_waitcnt vmcnt(8)" ::: "memory");
    __builtin_amdgcn_sched_barrier(0);
    __builtin_amdgcn_s_barrier();
    const bf16_t* sA = (const bf16_t*)((const char*)smem + (kt % 5) * 8192);
    const int s = kt % 3;
    #pragma unroll
    for (int kk = 0; kk < 2; ++kk){
      int uo = ((kk * 4 + ub) ^ key) * 8;
      bf16x8 a[4];
      #pragma unroll
      for (int mi = 0; mi < 4; ++mi)
        a[mi] = *reinterpret_cast<const bf16x8*>(sA + (mi * 16 + lr) * 64 + uo);
      #pragma unroll
      for (int mi = 0; mi < 4; ++mi){
        acc[mi][0] = __builtin_amdgcn_mfma_f32_16x16x32_bf16(a[mi], breg[s][0][kk], acc[mi][0], 0, 0, 0);
        acc[mi][1] = __builtin_amdgcn_mfma_f32_16x16x32_bf16(a[mi], breg[s][1][kk], acc[mi][1], 0, 0, 0);
      }
    }
    __builtin_amdgcn_s_barrier();
  }
  __syncthreads();   // full drain before LDS reuse as gbuf

  // epilogue: xconst (+ begin at t==0), gate exchange via LDS, fused cell
  int lg = lane >> 4;
  #pragma unroll
  for (int mi = 0; mi < 4; ++mi)
    #pragma unroll
    for (int ni = 0; ni < 2; ++ni)
      #pragma unroll
      for (int r = 0; r < 4; ++r){
        int cl = ni * 16 + lr;
        int ng = w * 1024 + cb * 32 + cl;
        int rl = mi * 16 + lg * 4 + r;
        int rowg = rb * 64 + rl;
        float v = acc[mi][ni][r] + xconst[(size_t)rowg * 4096 + ng];
        if (t == 0) v += w_ih[(size_t)ng * DINn + 1040];
        gbuf[(w * 64 + rl) * 33 + cl] = v;
      }
  __syncthreads();
  #pragma unroll
  for (int rep = 0; rep < 8; ++rep){
    int cell = tid + rep * 256;
    int rl = cell >> 5, cl = cell & 31;
    float gi = gbuf[(0 * 64 + rl) * 33 + cl];
    float gf = gbuf[(1 * 64 + rl) * 33 + cl];
    float gg = gbuf[(2 * 64 + rl) * 33 + cl];
    float go = gbuf[(3 * 64 + rl) * 33 + cl];
    int rowg = rb * 64 + rl, colg = cb * 32 + cl;
    size_t o = (size_t)rowg * 1024 + colg;
    float mo = m[o];
    float mn = sigm(gf) * mo + sigm(gi) * tanhf(gg);
    m[o] = mn;
    float hn = sigm(go) * tanhf(mn);
    hout[(size_t)rowg * HLD + colg] = (bf16_t)hn;
  }
}

// ---------- batched out GEMM (N=128) + XCD A-locality swizzle ----------
__global__ __launch_bounds__(256) void k_out(
    const bf16_t* __restrict__ h,      // hs + HSTEP: 24576 rows, stride 1088
    const bf16_t* __restrict__ fcwb,
    const float* __restrict__ fc_b, const int* __restrict__ length,
    float* __restrict__ out){
  __shared__ __align__(16) unsigned char smem[(BM + 128) * LDSP * 2];
  bf16_t* sA = (bf16_t*)smem;
  bf16_t* sB = (bf16_t*)(smem + BM * LDSP * 2);
  int tid = threadIdx.x;
  int id  = blockIdx.x;
  int xcd = id & 7;
  int rem = id >> 3;
  int cb  = rem % 9;
  int grp = rem / 9;
  int rb  = xcd + 8 * grp;               // 0..383
  f32x4 acc[4][2] = {};
  int lane = tid & 63, w = tid >> 6;
  for (int kt = 0; kt < 16; ++kt){
    stageAp(sA, h + (size_t)(rb * 64) * HLD + kt * 64, HLD, tid);
    #pragma unroll
    for (int i = 0; i < 4; ++i){
      int idx = tid + i * 256;
      int r = idx >> 3, v = idx & 7;
      int n = cb * 128 + r;
      bf16x8 val = {};
      if (n < NOn)
        val = *reinterpret_cast<const bf16x8*>(fcwb + (size_t)n * 1024 + kt * 64 + v * 8);
      *reinterpret_cast<bf16x8*>(sB + r * LDSP + v * 8) = val;
    }
    __syncthreads();
    mma_tile(sA, sB, acc, lane, w);
    __syncthreads();
  }
  int lr = lane & 15, lg = lane >> 4;
  #pragma unroll
  for (int mi = 0; mi < 4; ++mi)
    #pragma unroll
    for (int ni = 0; ni < 2; ++ni)
      #pragma unroll
      for (int r = 0; r < 4; ++r){
        int ng = cb * 128 + w * 32 + ni * 16 + lr;
        if (ng >= NOn) continue;
        int rg = rb * 64 + mi * 16 + lg * 4 + r;
        int tt = rg >> 9, b = rg & 511;
        float v = acc[mi][ni][r] + fc_b[ng];
        float mask = (tt < length[b]) ? 1.0f : 0.0f;
        if      (ng < 64)    out[(size_t)rg * 64 + ng] = sigm(v) * mask;
        else if (ng < 1088)  out[(size_t)1572864 + (size_t)rg * 1024 + (ng - 64)] = fmaxf(v, 0.f) * mask;
        else if (ng == 1088) out[(size_t)26738688 + rg] = sigm(v) * mask;
        else                 out[(size_t)26763264 + rg] = __expf(v) * mask;
      }
}

extern "C" void kernel_launch(void* const* d_in, const int* in_sizes, int n_in,
                              void* d_out, int out_size, void* d_ws, size_t ws_size,
                              hipStream_t stream){
  const float* image  = (const float*)d_in[0];
  const float* vp     = (const float*)d_in[1];
  const float* label  = (const float*)d_in[2];
  const int*   length = (const int*)  d_in[3];
  const float* fc_h_w = (const float*)d_in[4];
  const float* fc_h_b = (const float*)d_in[5];
  const float* fc_m_w = (const float*)d_in[6];
  const float* fc_m_b = (const float*)d_in[7];
  const float* w_ih   = (const float*)d_in[8];
  const float* w_hh   = (const float*)d_in[9];
  const float* b_ih   = (const float*)d_in[10];
  const float* b_hh   = (const float*)d_in[11];
  const float* fc_w   = (const float*)d_in[12];
  const float* fc_b   = (const float*)d_in[13];
  float* out = (float*)d_out;

  char* ws = (char*)d_ws;
  bf16_t* imb    = (bf16_t*)(ws + 0);           // 1 MB
  bf16_t* hs     = (bf16_t*)(ws + 1048576);     // 49 x 512 x 1088 bf16 = 54.6 MB
  float*  m      = (float*) (ws + 55640064);    // 2 MB
  float*  xconst = (float*) (ws + 57737216);    // 8 MB
  bf16_t* whht   = (bf16_t*)(ws + 66125824);    // packed 4096x1088 = 8.9 MB
  bf16_t* wimgb  = (bf16_t*)(ws + 75038720);    // 8 MB
  bf16_t* fchwb  = (bf16_t*)(ws + 83427328);    // 2 MB
  bf16_t* fcmwb  = (bf16_t*)(ws + 85524480);    // 2 MB
  bf16_t* fcwb   = (bf16_t*)(ws + 87621632);    // 2.2 MB (ends 89853952)

  k_mean   <<<dim3(512),  dim3(256), 0, stream>>>(image, imb);
  k_convert<<<dim3(2048), dim3(256), 0, stream>>>(w_hh, fc_h_w, fc_m_w, fc_w, label, w_ih,
                                                  whht, fchwb, fcmwb, fcwb, wimgb, hs);
  k_vpc    <<<dim3(8192), dim3(256), 0, stream>>>(w_ih, vp, b_ih, b_hh, xconst);
  k_init_gemm<<<dim3(48, 8), dim3(256), 0, stream>>>(imb, fchwb, fcmwb, wimgb,
                                                     fc_h_b, fc_m_b, hs, m, xconst);
  for (int t = 0; t < Tn; ++t){
    k_step<<<dim3(32, 8), dim3(256), 0, stream>>>(hs + (size_t)t * HSTEP,
                                                  hs + (size_t)(t + 1) * HSTEP,
                                                  whht, xconst, w_ih, m, t);
  }
  k_out<<<dim3(3456), dim3(256), 0, stream>>>(hs + (size_t)HSTEP, fcwb, fc_b, length, out);
}